// Round 2
// baseline (1834.974 us; speedup 1.0000x reference)
//
#include <hip/hip_runtime.h>

// ---------------------------------------------------------------------------
// TransformerBlock (linear attention + FFN) on MI355X — fp32, per-batch ws.
//
// Shapes: B=8, C=128, H=W=128 (L=16384), heads=16, head_dim=8, HID=340.
// Per-batch pipeline (b = 0..7, buffers reused across batches):
//   K1  ln1            : xn = LN(x_b)                        (XN)
//   K2  sgemm qkvo     : qkvo = Wqkvo·xn + b   (512ch)       (BIG)
//   K3  dw5 lepe       : lepe = dwconv5x5(v) + b             (LEPE)
//   K4  kvstats        : per-head sums of kv / mean_k / mean_v (STATS, atomic)
//   K5  attnmix        : attn_in = (res + lepe) * o_gate     (XN)
//   K6  sgemm proj     : x1 = Wp·attn_in + pb + x_b          (out_b)
//   K7  ln2            : xn2 = LN(x1)                        (XN)
//   K8  sgemm ffn_in   : p = Wf·xn2            (680ch)       (BIG)
//   K9  dw3+gate       : g = gelu(dw3(p_lo)) * dw3(p_hi)     (G)
//   K10 sgemm ffn_out  : out_b = Wo·g + x1                   (out_b in place)
//
// Workspace: ~83.7 MB (BIG 44.6 | XN 8.4 | LEPE 8.4 | G 22.3 | STATS 40KB)
// ---------------------------------------------------------------------------

static constexpr int C   = 128;
static constexpr int L   = 16384;   // 128*128
static constexpr int BN  = 8;       // batch
static constexpr float SCALE = 0.35355339f;  // 1/sqrt(8)

// ------------------------------ LayerNorm ----------------------------------
// One thread per pixel; loops channels (stride L).
__global__ __launch_bounds__(256) void ln_kernel(const float* __restrict__ x,
                                                 const float* __restrict__ w,
                                                 const float* __restrict__ bias,
                                                 float* __restrict__ y) {
  int l = blockIdx.x * 256 + threadIdx.x;   // pixel id in [0, L)
  const float* xb = x + l;
  float* yb = y + l;
  float s = 0.f, ss = 0.f;
#pragma unroll 8
  for (int c = 0; c < C; ++c) {
    float v = xb[(size_t)c * L];
    s += v; ss += v * v;
  }
  float mu = s * (1.f / C);
  float var = ss * (1.f / C) - mu * mu;
  float rstd = rsqrtf(var + 1e-5f);
#pragma unroll 8
  for (int c = 0; c < C; ++c) {
    float v = xb[(size_t)c * L];
    yb[(size_t)c * L] = (v - mu) * rstd * w[c] + bias[c];
  }
}

// ------------------------------ SGEMM --------------------------------------
// Y[o, l] = sum_k W[o,k] * X[k,l]  (+bias[o]) (+resid[o,l])  — per batch.
// 64x64 tile, BK=32, 256 threads, 4x4 microtile.
__global__ __launch_bounds__(256) void sgemm_kernel(
    const float* __restrict__ W, const float* __restrict__ X,
    float* __restrict__ Y, const float* __restrict__ bias,
    const float* __restrict__ resid, int O, int K) {
  const int tid = threadIdx.x;
  const int bl = blockIdx.x * 64;
  const int bo = blockIdx.y * 64;
  const float* Xb = X + bl;
  float* Yb = Y + bl;

  __shared__ float As[32][68];   // As[k][o]
  __shared__ float Bs[32][68];   // Bs[k][l]

  const int ty = tid >> 4, tx = tid & 15;
  const int ar = tid >> 3;          // 0..31
  const int ak = (tid & 7) << 2;    // 0..28
  const int bk = tid >> 4;          // 0..15
  const int bj = (tid & 15) << 2;   // 0..60

  float acc[4][4] = {};

  for (int k0 = 0; k0 < K; k0 += 32) {
#pragma unroll
    for (int rr = 0; rr < 2; ++rr) {
      int row = bo + ar + rr * 32;
      float4 v = make_float4(0.f, 0.f, 0.f, 0.f);
      if (row < O && (k0 + ak) < K)
        v = *reinterpret_cast<const float4*>(&W[(size_t)row * K + k0 + ak]);
      As[ak + 0][ar + rr * 32] = v.x;
      As[ak + 1][ar + rr * 32] = v.y;
      As[ak + 2][ar + rr * 32] = v.z;
      As[ak + 3][ar + rr * 32] = v.w;
    }
#pragma unroll
    for (int rr = 0; rr < 2; ++rr) {
      int krow = k0 + bk + rr * 16;
      float4 v = make_float4(0.f, 0.f, 0.f, 0.f);
      if (krow < K)
        v = *reinterpret_cast<const float4*>(&Xb[(size_t)krow * L + bj]);
      *reinterpret_cast<float4*>(&Bs[bk + rr * 16][bj]) = v;
    }
    __syncthreads();
#pragma unroll
    for (int kk = 0; kk < 32; ++kk) {
      float4 a  = *reinterpret_cast<const float4*>(&As[kk][ty << 2]);
      float4 bb = *reinterpret_cast<const float4*>(&Bs[kk][tx << 2]);
      float av[4] = {a.x, a.y, a.z, a.w};
      float bv[4] = {bb.x, bb.y, bb.z, bb.w};
#pragma unroll
      for (int i = 0; i < 4; ++i)
#pragma unroll
        for (int j = 0; j < 4; ++j) acc[i][j] = fmaf(av[i], bv[j], acc[i][j]);
    }
    __syncthreads();
  }

#pragma unroll
  for (int i = 0; i < 4; ++i) {
    int row = bo + (ty << 2) + i;
    if (row < O) {
      float4 r = make_float4(acc[i][0], acc[i][1], acc[i][2], acc[i][3]);
      if (bias) {
        float bv = bias[row];
        r.x += bv; r.y += bv; r.z += bv; r.w += bv;
      }
      if (resid) {
        float4 rv = *reinterpret_cast<const float4*>(
            &resid[(size_t)row * L + bl + (tx << 2)]);
        r.x += rv.x; r.y += rv.y; r.z += rv.z; r.w += rv.w;
      }
      *reinterpret_cast<float4*>(&Yb[(size_t)row * L + (tx << 2)]) = r;
    }
  }
}

// ------------------------- lepe: depthwise 5x5 -----------------------------
__global__ __launch_bounds__(256) void dw5_kernel(const float* __restrict__ qkvo,
                                                  const float* __restrict__ wdw,
                                                  const float* __restrict__ bdw,
                                                  float* __restrict__ outb) {
  int tile = blockIdx.x;            // 0..63
  int c = blockIdx.y;               // 0..127
  int ty0 = (tile >> 3) * 16, tx0 = (tile & 7) * 16;
  const float* in = qkvo + (size_t)(256 + c) * L;   // v channel c
  __shared__ float t[20][20];
  __shared__ float wc[25];
  int tid = threadIdx.x;
  if (tid < 25) wc[tid] = wdw[c * 25 + tid];
  for (int idx = tid; idx < 400; idx += 256) {
    int r = idx / 20, col = idx % 20;
    int gy = ty0 + r - 2, gx = tx0 + col - 2;
    float v = 0.f;
    if (gy >= 0 && gy < 128 && gx >= 0 && gx < 128) v = in[gy * 128 + gx];
    t[r][col] = v;
  }
  __syncthreads();
  int r = tid >> 4, col = tid & 15;
  float acc = 0.f;
#pragma unroll
  for (int i = 0; i < 5; ++i)
#pragma unroll
    for (int j = 0; j < 5; ++j) acc = fmaf(t[r + i][col + j], wc[i * 5 + j], acc);
  outb[(size_t)c * L + (ty0 + r) * 128 + tx0 + col] = acc + bdw[c];
}

// ------------------------------ RoPE helpers -------------------------------
__device__ inline void rope8(int l, float* sn, float* cs) {
  int h = l >> 7, w = l & 127;
  const float a4 = 1.0f / 10000.0f;
  float sh, ch, sh4, ch4, sw, cw, sw4, cw4;
  sincosf((float)h, &sh, &ch);
  sincosf((float)h * a4, &sh4, &ch4);
  sincosf((float)w, &sw, &cw);
  sincosf((float)w * a4, &sw4, &cw4);
  sn[0] = sh; sn[1] = sh; sn[2] = sh4; sn[3] = sh4;
  sn[4] = sw; sn[5] = sw; sn[6] = sw4; sn[7] = sw4;
  cs[0] = ch; cs[1] = ch; cs[2] = ch4; cs[3] = ch4;
  cs[4] = cw; cs[5] = cw; cs[6] = cw4; cs[7] = cw4;
}

__device__ inline void theta_shift8(const float* x, const float* sn,
                                    const float* cs, float* o) {
#pragma unroll
  for (int i = 0; i < 4; ++i) {
    float x0 = x[2 * i], x1 = x[2 * i + 1];
    o[2 * i]     = x0 * cs[2 * i]     - x1 * sn[2 * i];
    o[2 * i + 1] = x1 * cs[2 * i + 1] + x0 * sn[2 * i + 1];
  }
}

// ------------------- per-head kv / mean_k / mean_v sums --------------------
// stats[head][0..63]=sum kt·v^T, [64..71]=sum elu(k)+1, [72..79]=sum v
// grid: (32 l-chunks, 16 heads); atomicAdd into per-batch stats slice.
__global__ __launch_bounds__(256) void kvstats_kernel(const float* __restrict__ qkvo,
                                                      float* __restrict__ stats) {
  int n = blockIdx.y;                 // head 0..15
  int l0 = blockIdx.x * 512;
  int tid = threadIdx.x;
  const float* kb = qkvo + (size_t)(128 + n * 8) * L;
  const float* vb = qkvo + (size_t)(256 + n * 8) * L;
  float kv[8][8] = {};
  float mk[8] = {}, mv[8] = {};
  for (int l = l0 + tid; l < l0 + 512; l += 256) {
    float sn[8], cs[8];
    rope8(l, sn, cs);
    float ke[8], kt[8], vv[8];
#pragma unroll
    for (int d = 0; d < 8; ++d) {
      float kval = kb[(size_t)d * L + l];
      ke[d] = kval > 0.f ? kval + 1.f : expf(kval);
      mk[d] += ke[d];
      vv[d] = vb[(size_t)d * L + l];
      mv[d] += vv[d];
    }
    theta_shift8(ke, sn, cs, kt);
#pragma unroll
    for (int d = 0; d < 8; ++d)
#pragma unroll
      for (int e = 0; e < 8; ++e) kv[d][e] = fmaf(kt[d], vv[e], kv[d][e]);
  }
  float vals[80];
#pragma unroll
  for (int d = 0; d < 8; ++d)
#pragma unroll
    for (int e = 0; e < 8; ++e) vals[d * 8 + e] = kv[d][e];
#pragma unroll
  for (int d = 0; d < 8; ++d) { vals[64 + d] = mk[d]; vals[72 + d] = mv[d]; }
#pragma unroll
  for (int i = 0; i < 80; ++i) {
    float v = vals[i];
#pragma unroll
    for (int off = 32; off > 0; off >>= 1) v += __shfl_down(v, off);
    vals[i] = v;
  }
  __shared__ float red[4][80];
  int lane = tid & 63, wid = tid >> 6;
  if (lane == 0) {
#pragma unroll
    for (int i = 0; i < 80; ++i) red[wid][i] = vals[i];
  }
  __syncthreads();
  if (tid < 80) {
    float s2 = red[0][tid] + red[1][tid] + red[2][tid] + red[3][tid];
    atomicAdd(&stats[n * 80 + tid], s2);
  }
}

// -------- attn mix: res = q~·kv*(1+1/z) - z*mean_v; out=(res+lepe)*o -------
__global__ __launch_bounds__(256) void attnmix_kernel(const float* __restrict__ qkvo,
                                                      const float* __restrict__ lepe,
                                                      const float* __restrict__ stats,
                                                      float* __restrict__ outb) {
  int n = blockIdx.y;                 // head 0..15
  int tid = threadIdx.x;
  __shared__ float kvs[64], mks[8], mvs[8];
  if (tid < 64)       kvs[tid]      = stats[n * 80 + tid] * (SCALE / (float)L);
  else if (tid < 72)  mks[tid - 64] = stats[n * 80 + tid] * (1.f / (float)L);
  else if (tid < 80)  mvs[tid - 72] = stats[n * 80 + tid] * (1.f / (float)L);
  __syncthreads();
  int l = blockIdx.x * 256 + tid;
  const float* qb = qkvo + (size_t)(n * 8) * L + l;
  const float* ob = qkvo + (size_t)(384 + n * 8) * L + l;
  const float* lb = lepe + (size_t)(n * 8) * L + l;
  float* yb = outb + (size_t)(n * 8) * L + l;
  float qe[8];
#pragma unroll
  for (int d = 0; d < 8; ++d) {
    float qv = qb[(size_t)d * L];
    qe[d] = qv > 0.f ? qv + 1.f : expf(qv);
  }
  float z = 0.f;
#pragma unroll
  for (int d = 0; d < 8; ++d) z += qe[d] * mks[d];
  z *= SCALE;
  float sn[8], cs[8];
  rope8(l, sn, cs);
  float qt[8];
  theta_shift8(qe, sn, cs, qt);
  float coef = 1.f + 1.f / (z + 1e-6f);
#pragma unroll
  for (int e = 0; e < 8; ++e) {
    float r = 0.f;
#pragma unroll
    for (int d = 0; d < 8; ++d) r = fmaf(qt[d], kvs[d * 8 + e], r);
    float res = r * coef - z * mvs[e];
    yb[(size_t)e * L] = (res + lb[(size_t)e * L]) * ob[(size_t)e * L];
  }
}

// ---------------- FFN: depthwise 3x3 on channel pair + GELU gate -----------
__global__ __launch_bounds__(256) void dw3gate_kernel(const float* __restrict__ p,
                                                      const float* __restrict__ wdw,
                                                      float* __restrict__ g) {
  int tile = blockIdx.x;           // 0..63
  int c = blockIdx.y;              // 0..339
  int ty0 = (tile >> 3) * 16, tx0 = (tile & 7) * 16;
  const float* inA = p + (size_t)c * L;
  const float* inB = p + (size_t)(340 + c) * L;
  __shared__ float ta[18][18];
  __shared__ float tb[18][18];
  __shared__ float wa[9], wb[9];
  int tid = threadIdx.x;
  if (tid < 9)        wa[tid]     = wdw[c * 9 + tid];
  else if (tid < 18)  wb[tid - 9] = wdw[(340 + c) * 9 + (tid - 9)];
  for (int idx = tid; idx < 324; idx += 256) {
    int r = idx / 18, col = idx % 18;
    int gy = ty0 + r - 1, gx = tx0 + col - 1;
    bool ok = (gy >= 0 && gy < 128 && gx >= 0 && gx < 128);
    ta[r][col] = ok ? inA[gy * 128 + gx] : 0.f;
    tb[r][col] = ok ? inB[gy * 128 + gx] : 0.f;
  }
  __syncthreads();
  int r = tid >> 4, col = tid & 15;
  float a = 0.f, b2 = 0.f;
#pragma unroll
  for (int i = 0; i < 3; ++i)
#pragma unroll
    for (int j = 0; j < 3; ++j) {
      a  = fmaf(ta[r + i][col + j], wa[i * 3 + j], a);
      b2 = fmaf(tb[r + i][col + j], wb[i * 3 + j], b2);
    }
  float ge = 0.5f * a * (1.f + erff(a * 0.70710678f));
  g[(size_t)c * L + (ty0 + r) * 128 + tx0 + col] = ge * b2;
}

// ---------------------------------------------------------------------------
extern "C" void kernel_launch(void* const* d_in, const int* in_sizes, int n_in,
                              void* d_out, int out_size, void* d_ws, size_t ws_size,
                              hipStream_t stream) {
  const float* x        = (const float*)d_in[0];
  const float* ln1_w    = (const float*)d_in[1];
  const float* ln1_b    = (const float*)d_in[2];
  const float* qkvo_w   = (const float*)d_in[3];
  const float* qkvo_b   = (const float*)d_in[4];
  const float* lepe_w   = (const float*)d_in[5];
  const float* lepe_b   = (const float*)d_in[6];
  const float* proj_w   = (const float*)d_in[7];
  const float* proj_b   = (const float*)d_in[8];
  const float* ln2_w    = (const float*)d_in[9];
  const float* ln2_b    = (const float*)d_in[10];
  const float* ffn_in_w = (const float*)d_in[11];
  const float* ffn_dw_w = (const float*)d_in[12];
  const float* ffn_out_w= (const float*)d_in[13];
  float* out = (float*)d_out;

  // per-batch workspace layout (bytes)
  const size_t BIG_OFF   = 0;               // 44,564,480 (qkvo 512ch / p 680ch)
  const size_t XN_OFF    = 44564480ull;     //  8,388,608 (xn / attn_in / xn2)
  const size_t LEPE_OFF  = 52953088ull;     //  8,388,608
  const size_t G_OFF     = 61341696ull;     // 22,282,240
  const size_t STATS_OFF = 83623936ull;     //     40,960 (all 8 batches)
  const size_t NEEDED    = 83664896ull;     // ~83.7 MB
  if (ws_size < NEEDED) return;  // clean validation failure instead of OOB

  char* ws = (char*)d_ws;
  float* big   = (float*)(ws + BIG_OFF);
  float* xnbuf = (float*)(ws + XN_OFF);
  float* lepeb = (float*)(ws + LEPE_OFF);
  float* gbuf  = (float*)(ws + G_OFF);
  float* stats = (float*)(ws + STATS_OFF);

  // zero all per-head stat slots once (atomicAdd accumulates per batch)
  hipMemsetAsync(stats, 0, 128 * 80 * sizeof(float), stream);

  for (int b = 0; b < BN; ++b) {
    const float* xb   = x   + (size_t)b * C * L;
    float*       outb = out + (size_t)b * C * L;
    float*       st_b = stats + (size_t)b * 16 * 80;

    // K1: LN1 -> xn
    ln_kernel<<<dim3(64), 256, 0, stream>>>(xb, ln1_w, ln1_b, xnbuf);
    // K2: qkvo GEMM (O=512, K=128) -> big
    sgemm_kernel<<<dim3(256, 8), 256, 0, stream>>>(qkvo_w, xnbuf, big,
                                                   qkvo_b, nullptr, 512, 128);
    // K3: lepe dwconv 5x5 on v -> lepe
    dw5_kernel<<<dim3(64, 128), 256, 0, stream>>>(big, lepe_w, lepe_b, lepeb);
    // K4: per-head stats (atomic into this batch's slots)
    kvstats_kernel<<<dim3(32, 16), 256, 0, stream>>>(big, st_b);
    // K5: attention mix -> attn_in (reuse XN)
    attnmix_kernel<<<dim3(64, 16), 256, 0, stream>>>(big, lepeb, st_b, xnbuf);
    // K6: proj GEMM + residual x -> out (x1)
    sgemm_kernel<<<dim3(256, 2), 256, 0, stream>>>(proj_w, xnbuf, outb,
                                                   proj_b, xb, 128, 128);
    // K7: LN2 -> xn2 (reuse XN)
    ln_kernel<<<dim3(64), 256, 0, stream>>>(outb, ln2_w, ln2_b, xnbuf);
    // K8: ffn_in GEMM (O=680, K=128) -> p (reuse BIG)
    sgemm_kernel<<<dim3(256, 11), 256, 0, stream>>>(ffn_in_w, xnbuf, big,
                                                    nullptr, nullptr, 680, 128);
    // K9: dwconv3x3 + GELU gate -> g
    dw3gate_kernel<<<dim3(64, 340), 256, 0, stream>>>(big, ffn_dw_w, gbuf);
    // K10: ffn_out GEMM (O=128, K=340) + residual x1 -> out (in place)
    sgemm_kernel<<<dim3(256, 2), 256, 0, stream>>>(ffn_out_w, gbuf, outb,
                                                   nullptr, outb, 128, 340);
  }
}

// Round 4
// 1737.303 us; speedup vs baseline: 1.0562x; 1.0562x over previous
//
#include <hip/hip_runtime.h>

// ---------------------------------------------------------------------------
// TransformerBlock (linear attention + FFN) on MI355X — bf16 MFMA GEMMs,
// LDS-free GEMM reading pre-transposed activations XT[pixel][c].
//
// Shapes: B=8, C=128, H=W=128 (L=16384), heads=16, head_dim=8, HID=340.
// GEMM: D[pixel][o] = sum_k XT[pixel][k] * W[o][k], via mfma_f32_16x16x32_bf16.
//   A-frag: lane l = pixel row (l&15), slots k = 8g+j  (16B global load)
//   B-frag: lane l = o col    (l&15), slots k = 8g+j  (16B global load)
//   (identical slot permutation on A and B => correct for any HW slot map)
//   C/D: col(o) = lane&15, row(pixel) = (lane>>4)*4 + reg   [m89-verified]
// ---------------------------------------------------------------------------

static constexpr int C   = 128;
static constexpr int L   = 16384;   // 128*128
static constexpr int BN  = 8;       // batch
static constexpr float SCALE = 0.35355339f;  // 1/sqrt(8)

typedef short bf16x8 __attribute__((ext_vector_type(8)));
typedef float f32x4  __attribute__((ext_vector_type(4)));

union ABFrag { bf16x8 v; uint4 q; };
union U4S8   { uint4 q; short s[8]; };

__device__ inline short f2bf(float f) {
  unsigned u = __float_as_uint(f);
  u += 0x7FFFu + ((u >> 16) & 1u);
  return (short)(u >> 16);
}
__device__ inline float bf2f(short s) {
  return __uint_as_float(((unsigned)(unsigned short)s) << 16);
}

// ------------------------- weight fp32 -> bf16 (K-pad) ---------------------
__global__ __launch_bounds__(256) void convert_w(const float* __restrict__ src,
                                                 short* __restrict__ dst,
                                                 int O, int K, int Kp) {
  int idx = blockIdx.x * 256 + threadIdx.x;
  if (idx >= O * Kp) return;
  int o = idx / Kp, k = idx - o * Kp;
  dst[idx] = (k < K) ? f2bf(src[o * K + k]) : (short)0;
}

// ------------------------------ MFMA GEMM ----------------------------------
// Y[o][l] = sum_k W[o][k] * XT[l][k]  (+bias) (+resid). No LDS.
// Block tile: 128 l x 64 o, 4 waves (2l x 2o), wave = 64l x 32o, BK=32.
template <int OUT_BF16, int HAS_BIAS, int HAS_RESID>
__global__ __launch_bounds__(256) void mfma_gemm(
    const short* __restrict__ XT, const short* __restrict__ Wb,
    void* __restrict__ Yv, const float* __restrict__ bias,
    const float* __restrict__ resid, int O, int Kp) {
  const int lane = threadIdx.x & 63;
  const int wid  = threadIdx.x >> 6;
  const int wl = wid & 1, wo = wid >> 1;
  const int bl = blockIdx.x * 128;
  const int bo = blockIdx.y * 64;
  const int g   = lane >> 4;
  const int r15 = lane & 15;

  f32x4 acc[4][2];
#pragma unroll
  for (int m = 0; m < 4; ++m)
#pragma unroll
    for (int n = 0; n < 2; ++n) acc[m][n] = (f32x4){0.f, 0.f, 0.f, 0.f};

  const short* xrow[4];
#pragma unroll
  for (int m = 0; m < 4; ++m)
    xrow[m] = XT + (size_t)(bl + wl * 64 + m * 16 + r15) * Kp + g * 8;
  const short* wrow[2];
#pragma unroll
  for (int n = 0; n < 2; ++n)
    wrow[n] = Wb + (size_t)(bo + wo * 32 + n * 16 + r15) * Kp + g * 8;
  // note: for O=680 the last block reads up to 24 rows past W (still inside
  // the workspace; values multiplied into lanes whose results are discarded).

  for (int k0 = 0; k0 < Kp; k0 += 32) {
    ABFrag a[4], b[2];
#pragma unroll
    for (int m = 0; m < 4; ++m) a[m].q = *(const uint4*)(xrow[m] + k0);
#pragma unroll
    for (int n = 0; n < 2; ++n) b[n].q = *(const uint4*)(wrow[n] + k0);
#pragma unroll
    for (int m = 0; m < 4; ++m)
#pragma unroll
      for (int n = 0; n < 2; ++n)
        acc[m][n] = __builtin_amdgcn_mfma_f32_16x16x32_bf16(a[m].v, b[n].v,
                                                            acc[m][n], 0, 0, 0);
  }

  // epilogue: D col = o (lane&15), D row = pixel ((lane>>4)*4 + reg)
#pragma unroll
  for (int n = 0; n < 2; ++n) {
    int o = bo + wo * 32 + n * 16 + r15;
    if (o >= O) continue;
    float bv = HAS_BIAS ? bias[o] : 0.f;
#pragma unroll
    for (int m = 0; m < 4; ++m) {
      int l = bl + wl * 64 + m * 16 + (g << 2);
      f32x4 v = acc[m][n];
      if (HAS_BIAS) { v[0] += bv; v[1] += bv; v[2] += bv; v[3] += bv; }
      if (HAS_RESID) {
        const float4 r = *(const float4*)(resid + (size_t)o * L + l);
        v[0] += r.x; v[1] += r.y; v[2] += r.z; v[3] += r.w;
      }
      if (OUT_BF16) {
        uint2 s;
        s.x = (unsigned short)f2bf(v[0]) | ((unsigned)(unsigned short)f2bf(v[1]) << 16);
        s.y = (unsigned short)f2bf(v[2]) | ((unsigned)(unsigned short)f2bf(v[3]) << 16);
        *(uint2*)((short*)Yv + (size_t)o * L + l) = s;
      } else {
        *(float4*)((float*)Yv + (size_t)o * L + l) = make_float4(v[0], v[1], v[2], v[3]);
      }
    }
  }
}

// ------------------------------ LayerNorm ----------------------------------
// One thread per pixel; fp32 in [c][l], bf16 out XT[l][c].
__global__ __launch_bounds__(256) void ln_xt(const float* __restrict__ x,
                                             const float* __restrict__ w,
                                             const float* __restrict__ bias,
                                             short* __restrict__ yt) {
  int l = blockIdx.x * 256 + threadIdx.x;
  const float* xb = x + l;
  float s = 0.f, ss = 0.f;
#pragma unroll 8
  for (int c = 0; c < C; ++c) {
    float v = xb[(size_t)c * L];
    s += v; ss += v * v;
  }
  float mu = s * (1.f / C);
  float var = ss * (1.f / C) - mu * mu;
  float rstd = rsqrtf(var + 1e-5f);
  short* yr = yt + (size_t)l * C;
  for (int c0 = 0; c0 < C; c0 += 8) {
    U4S8 u;
#pragma unroll
    for (int j = 0; j < 8; ++j) {
      float v = xb[(size_t)(c0 + j) * L];
      u.s[j] = f2bf((v - mu) * rstd * w[c0 + j] + bias[c0 + j]);
    }
    *(uint4*)(yr + c0) = u.q;
  }
}

// ------------------------- lepe: depthwise 5x5 -----------------------------
__global__ __launch_bounds__(256) void dw5_kernel(const float* __restrict__ qkvo,
                                                  const float* __restrict__ wdw,
                                                  const float* __restrict__ bdw,
                                                  float* __restrict__ outb) {
  int tile = blockIdx.x;            // 0..63
  int c = blockIdx.y;               // 0..127
  int ty0 = (tile >> 3) * 16, tx0 = (tile & 7) * 16;
  const float* in = qkvo + (size_t)(256 + c) * L;   // v channel c
  __shared__ float t[20][20];
  __shared__ float wc[25];
  int tid = threadIdx.x;
  if (tid < 25) wc[tid] = wdw[c * 25 + tid];
  for (int idx = tid; idx < 400; idx += 256) {
    int r = idx / 20, col = idx % 20;
    int gy = ty0 + r - 2, gx = tx0 + col - 2;
    float v = 0.f;
    if (gy >= 0 && gy < 128 && gx >= 0 && gx < 128) v = in[gy * 128 + gx];
    t[r][col] = v;
  }
  __syncthreads();
  int r = tid >> 4, col = tid & 15;
  float acc = 0.f;
#pragma unroll
  for (int i = 0; i < 5; ++i)
#pragma unroll
    for (int j = 0; j < 5; ++j) acc = fmaf(t[r + i][col + j], wc[i * 5 + j], acc);
  outb[(size_t)c * L + (ty0 + r) * 128 + tx0 + col] = acc + bdw[c];
}

// ------------------------------ RoPE helpers -------------------------------
__device__ inline void rope8(int l, float* sn, float* cs) {
  int h = l >> 7, w = l & 127;
  const float a4 = 1.0f / 10000.0f;
  float sh, ch, sh4, ch4, sw, cw, sw4, cw4;
  sincosf((float)h, &sh, &ch);
  sincosf((float)h * a4, &sh4, &ch4);
  sincosf((float)w, &sw, &cw);
  sincosf((float)w * a4, &sw4, &cw4);
  sn[0] = sh; sn[1] = sh; sn[2] = sh4; sn[3] = sh4;
  sn[4] = sw; sn[5] = sw; sn[6] = sw4; sn[7] = sw4;
  cs[0] = ch; cs[1] = ch; cs[2] = ch4; cs[3] = ch4;
  cs[4] = cw; cs[5] = cw; cs[6] = cw4; cs[7] = cw4;
}

__device__ inline void theta_shift8(const float* x, const float* sn,
                                    const float* cs, float* o) {
#pragma unroll
  for (int i = 0; i < 4; ++i) {
    float x0 = x[2 * i], x1 = x[2 * i + 1];
    o[2 * i]     = x0 * cs[2 * i]     - x1 * sn[2 * i];
    o[2 * i + 1] = x1 * cs[2 * i + 1] + x0 * sn[2 * i + 1];
  }
}

// ------------------- per-head kv / mean_k / mean_v sums --------------------
__global__ __launch_bounds__(256) void kvstats_kernel(const float* __restrict__ qkvo,
                                                      float* __restrict__ stats) {
  int n = blockIdx.y;                 // head 0..15
  int l0 = blockIdx.x * 512;
  int tid = threadIdx.x;
  const float* kb = qkvo + (size_t)(128 + n * 8) * L;
  const float* vb = qkvo + (size_t)(256 + n * 8) * L;
  float kv[8][8] = {};
  float mk[8] = {}, mv[8] = {};
  for (int l = l0 + tid; l < l0 + 512; l += 256) {
    float sn[8], cs[8];
    rope8(l, sn, cs);
    float ke[8], kt[8], vv[8];
#pragma unroll
    for (int d = 0; d < 8; ++d) {
      float kval = kb[(size_t)d * L + l];
      ke[d] = kval > 0.f ? kval + 1.f : expf(kval);
      mk[d] += ke[d];
      vv[d] = vb[(size_t)d * L + l];
      mv[d] += vv[d];
    }
    theta_shift8(ke, sn, cs, kt);
#pragma unroll
    for (int d = 0; d < 8; ++d)
#pragma unroll
      for (int e = 0; e < 8; ++e) kv[d][e] = fmaf(kt[d], vv[e], kv[d][e]);
  }
  float vals[80];
#pragma unroll
  for (int d = 0; d < 8; ++d)
#pragma unroll
    for (int e = 0; e < 8; ++e) vals[d * 8 + e] = kv[d][e];
#pragma unroll
  for (int d = 0; d < 8; ++d) { vals[64 + d] = mk[d]; vals[72 + d] = mv[d]; }
#pragma unroll
  for (int i = 0; i < 80; ++i) {
    float v = vals[i];
#pragma unroll
    for (int off = 32; off > 0; off >>= 1) v += __shfl_down(v, off);
    vals[i] = v;
  }
  __shared__ float red[4][80];
  int lane = tid & 63, wid = tid >> 6;
  if (lane == 0) {
#pragma unroll
    for (int i = 0; i < 80; ++i) red[wid][i] = vals[i];
  }
  __syncthreads();
  if (tid < 80) {
    float s2 = red[0][tid] + red[1][tid] + red[2][tid] + red[3][tid];
    atomicAdd(&stats[n * 80 + tid], s2);
  }
}

// --- attn mix: res = q~·kv*(1+1/z) - z*mean_v; XT out = (res+lepe)*o_gate ---
__global__ __launch_bounds__(256) void attnmix_kernel(const float* __restrict__ qkvo,
                                                      const float* __restrict__ lepe,
                                                      const float* __restrict__ stats,
                                                      short* __restrict__ outt) {
  int n = blockIdx.y;                 // head 0..15
  int tid = threadIdx.x;
  __shared__ float kvs[64], mks[8], mvs[8];
  if (tid < 64)       kvs[tid]      = stats[n * 80 + tid] * (SCALE / (float)L);
  else if (tid < 72)  mks[tid - 64] = stats[n * 80 + tid] * (1.f / (float)L);
  else if (tid < 80)  mvs[tid - 72] = stats[n * 80 + tid] * (1.f / (float)L);
  __syncthreads();
  int l = blockIdx.x * 256 + tid;
  const float* qb = qkvo + (size_t)(n * 8) * L + l;
  const float* ob = qkvo + (size_t)(384 + n * 8) * L + l;
  const float* lb = lepe + (size_t)(n * 8) * L + l;
  float qe[8];
#pragma unroll
  for (int d = 0; d < 8; ++d) {
    float qv = qb[(size_t)d * L];
    qe[d] = qv > 0.f ? qv + 1.f : expf(qv);
  }
  float z = 0.f;
#pragma unroll
  for (int d = 0; d < 8; ++d) z += qe[d] * mks[d];
  z *= SCALE;
  float sn[8], cs[8];
  rope8(l, sn, cs);
  float qt[8];
  theta_shift8(qe, sn, cs, qt);
  float coef = 1.f + 1.f / (z + 1e-6f);
  U4S8 u;
#pragma unroll
  for (int e = 0; e < 8; ++e) {
    float r = 0.f;
#pragma unroll
    for (int d = 0; d < 8; ++d) r = fmaf(qt[d], kvs[d * 8 + e], r);
    float res = r * coef - z * mvs[e];
    u.s[e] = f2bf((res + lb[(size_t)e * L]) * ob[(size_t)e * L]);
  }
  *(uint4*)(outt + (size_t)l * C + n * 8) = u.q;   // XT[l][n*8..n*8+8)
}

// ---------------- FFN: depthwise 3x3 + GELU gate -> XT[l][352] -------------
// grid (64 pixel tiles, 44 c-chunks of 8); thread = pixel in 16x16 tile.
__global__ __launch_bounds__(256) void dw3gate_kernel(const short* __restrict__ p,
                                                      const float* __restrict__ wdw,
                                                      short* __restrict__ gxt) {
  int tile = blockIdx.x;           // 0..63
  int c0 = blockIdx.y * 8;         // 0..344
  int ty0 = (tile >> 3) * 16, tx0 = (tile & 7) * 16;
  __shared__ short ta[8][18][18];
  __shared__ short tb[8][18][18];
  __shared__ float wa[8][9], wb[8][9];
  int tid = threadIdx.x;
  if (tid < 144) {
    int ch = tid / 9, j = tid % 9, half = 0;
    if (ch >= 8) { ch -= 8; half = 1; }
    int c = c0 + ch;
    float wv = (c < 340) ? wdw[(half * 340 + c) * 9 + j] : 0.f;
    if (half) wb[ch][j] = wv; else wa[ch][j] = wv;
  }
  for (int idx = tid; idx < 8 * 324; idx += 256) {
    int ch = idx / 324, e = idx - ch * 324;
    int r = e / 18, col = e - r * 18;
    int c = c0 + ch;
    int gy = ty0 + r - 1, gx = tx0 + col - 1;
    bool ok = (c < 340) && gy >= 0 && gy < 128 && gx >= 0 && gx < 128;
    ta[ch][r][col] = ok ? p[(size_t)c * L + gy * 128 + gx] : (short)0;
    tb[ch][r][col] = ok ? p[(size_t)(340 + c) * L + gy * 128 + gx] : (short)0;
  }
  __syncthreads();
  int r = tid >> 4, col = tid & 15;
  U4S8 u;
#pragma unroll
  for (int ch = 0; ch < 8; ++ch) {
    float a = 0.f, b2 = 0.f;
#pragma unroll
    for (int i = 0; i < 3; ++i)
#pragma unroll
      for (int j = 0; j < 3; ++j) {
        a  = fmaf(bf2f(ta[ch][r + i][col + j]), wa[ch][i * 3 + j], a);
        b2 = fmaf(bf2f(tb[ch][r + i][col + j]), wb[ch][i * 3 + j], b2);
      }
    float ge = 0.5f * a * (1.f + erff(a * 0.70710678f));
    u.s[ch] = f2bf(ge * b2);
  }
  int pix = (ty0 + r) * 128 + tx0 + col;
  *(uint4*)(gxt + (size_t)pix * 352 + c0) = u.q;
}

// ---------------------------------------------------------------------------
extern "C" void kernel_launch(void* const* d_in, const int* in_sizes, int n_in,
                              void* d_out, int out_size, void* d_ws, size_t ws_size,
                              hipStream_t stream) {
  const float* x        = (const float*)d_in[0];
  const float* ln1_w    = (const float*)d_in[1];
  const float* ln1_b    = (const float*)d_in[2];
  const float* qkvo_w   = (const float*)d_in[3];
  const float* qkvo_b   = (const float*)d_in[4];
  const float* lepe_w   = (const float*)d_in[5];
  const float* lepe_b   = (const float*)d_in[6];
  const float* proj_w   = (const float*)d_in[7];
  const float* proj_b   = (const float*)d_in[8];
  const float* ln2_w    = (const float*)d_in[9];
  const float* ln2_b    = (const float*)d_in[10];
  const float* ffn_in_w = (const float*)d_in[11];
  const float* ffn_dw_w = (const float*)d_in[12];
  const float* ffn_out_w= (const float*)d_in[13];
  float* out = (float*)d_out;

  // workspace layout (bytes)
  const size_t QKVO_OFF = 0;              // 33,554,432 fp32 [512][L]
  const size_t XN_OFF   = 33554432ull;    //  4,194,304 bf16 XT [L][128]
  const size_t LEPE_OFF = 37748736ull;    //  8,388,608 fp32 [128][L]
  const size_t P_OFF    = 46137344ull;    // 22,282,240 bf16 [680][L]
  const size_t G_OFF    = 68419584ull;    // 11,534,336 bf16 XT [L][352]
  const size_t STAT_OFF = 79953920ull;    //     40,960 fp32 [8][16][80]
  const size_t WQ_OFF   = 79994880ull;    //    131,072 bf16 [512][128]
  const size_t WP_OFF   = 80125952ull;    //     32,768 bf16 [128][128]
  const size_t WFI_OFF  = 80158720ull;    //    174,080 bf16 [680][128]
  const size_t WFO_OFF  = 80332800ull;    //     90,112 bf16 [128][352]
  const size_t NEEDED   = 80422912ull;
  if (ws_size < NEEDED) return;

  char* ws = (char*)d_ws;
  float* qbuf  = (float*)(ws + QKVO_OFF);
  short* xnbuf = (short*)(ws + XN_OFF);
  float* lepeb = (float*)(ws + LEPE_OFF);
  short* pbuf  = (short*)(ws + P_OFF);
  short* gxt   = (short*)(ws + G_OFF);
  float* stats = (float*)(ws + STAT_OFF);
  short* wq    = (short*)(ws + WQ_OFF);
  short* wp    = (short*)(ws + WP_OFF);
  short* wfi   = (short*)(ws + WFI_OFF);
  short* wfo   = (short*)(ws + WFO_OFF);

  convert_w<<<dim3((512 * 128 + 255) / 256), 256, 0, stream>>>(qkvo_w, wq, 512, 128, 128);
  convert_w<<<dim3((128 * 128 + 255) / 256), 256, 0, stream>>>(proj_w, wp, 128, 128, 128);
  convert_w<<<dim3((680 * 128 + 255) / 256), 256, 0, stream>>>(ffn_in_w, wfi, 680, 128, 128);
  convert_w<<<dim3((128 * 352 + 255) / 256), 256, 0, stream>>>(ffn_out_w, wfo, 128, 340, 352);
  hipMemsetAsync(stats, 0, 128 * 80 * sizeof(float), stream);

  for (int b = 0; b < BN; ++b) {
    const float* xb   = x   + (size_t)b * C * L;
    float*       outb = out + (size_t)b * C * L;
    float*       st_b = stats + (size_t)b * 16 * 80;

    // K1: LN1 -> xn XT (bf16)
    ln_xt<<<dim3(64), 256, 0, stream>>>(xb, ln1_w, ln1_b, xnbuf);
    // K2: qkvo GEMM (O=512, K=128) -> qbuf fp32 [512][L]
    mfma_gemm<0, 1, 0><<<dim3(128, 8), 256, 0, stream>>>(xnbuf, wq, qbuf,
                                                         qkvo_b, nullptr, 512, 128);
    // K3: lepe dwconv 5x5 on v -> lepe fp32
    dw5_kernel<<<dim3(64, 128), 256, 0, stream>>>(qbuf, lepe_w, lepe_b, lepeb);
    // K4: per-head stats
    kvstats_kernel<<<dim3(32, 16), 256, 0, stream>>>(qbuf, st_b);
    // K5: attention mix -> attn_in XT (bf16, reuse XN)
    attnmix_kernel<<<dim3(64, 16), 256, 0, stream>>>(qbuf, lepeb, st_b, xnbuf);
    // K6: proj GEMM + bias + residual x -> out (fp32 x1)
    mfma_gemm<0, 1, 1><<<dim3(128, 2), 256, 0, stream>>>(xnbuf, wp, outb,
                                                         proj_b, xb, 128, 128);
    // K7: LN2 -> xn2 XT (bf16, reuse XN)
    ln_xt<<<dim3(64), 256, 0, stream>>>(outb, ln2_w, ln2_b, xnbuf);
    // K8: ffn_in GEMM (O=680, K=128) -> p (bf16 [680][L])
    mfma_gemm<1, 0, 0><<<dim3(128, 11), 256, 0, stream>>>(xnbuf, wfi, pbuf,
                                                          nullptr, nullptr, 680, 128);
    // K9: dwconv3x3 + GELU gate -> g XT [L][352] (pads 340..351 zeroed)
    dw3gate_kernel<<<dim3(64, 44), 256, 0, stream>>>(pbuf, ffn_dw_w, gxt);
    // K10: ffn_out GEMM (O=128, Kp=352) + residual x1 -> out (in place)
    mfma_gemm<0, 0, 1><<<dim3(128, 2), 256, 0, stream>>>(gxt, wfo, outb,
                                                         nullptr, outb, 128, 352);
  }
}

// Round 5
// 1266.532 us; speedup vs baseline: 1.4488x; 1.3717x over previous
//
#include <hip/hip_runtime.h>

// ---------------------------------------------------------------------------
// TransformerBlock (linear attention + FFN) on MI355X — bf16 MFMA GEMMs,
// LDS-free GEMM reading pre-transposed activations XT[pixel][c].
// R4: stripe-based dwconvs (coalesced vector loads), 4-wave LN, rope tables.
// ---------------------------------------------------------------------------

static constexpr int C   = 128;
static constexpr int L   = 16384;   // 128*128
static constexpr int BN  = 8;       // batch
static constexpr float SCALE = 0.35355339f;  // 1/sqrt(8)

typedef short bf16x8 __attribute__((ext_vector_type(8)));
typedef float f32x4  __attribute__((ext_vector_type(4)));

union ABFrag { bf16x8 v; uint4 q; };
union U4S8   { uint4 q; short s[8]; };
union U2S4   { uint2 q; short s[4]; };

__device__ inline short f2bf(float f) {
  unsigned u = __float_as_uint(f);
  u += 0x7FFFu + ((u >> 16) & 1u);
  return (short)(u >> 16);
}
__device__ inline float bf2f(short s) {
  return __uint_as_float(((unsigned)(unsigned short)s) << 16);
}

// ------------------------- weight fp32 -> bf16 (K-pad) ---------------------
__global__ __launch_bounds__(256) void convert_w(const float* __restrict__ src,
                                                 short* __restrict__ dst,
                                                 int O, int K, int Kp) {
  int idx = blockIdx.x * 256 + threadIdx.x;
  if (idx >= O * Kp) return;
  int o = idx / Kp, k = idx - o * Kp;
  dst[idx] = (k < K) ? f2bf(src[o * K + k]) : (short)0;
}

// ------------------------------ MFMA GEMM ----------------------------------
// Y[o][l] = sum_k W[o][k] * XT[l][k]  (+bias) (+resid). No LDS.
// Block tile: 128 l x 64 o, 4 waves (2l x 2o), wave = 64l x 32o, BK=32.
template <int OUT_BF16, int HAS_BIAS, int HAS_RESID>
__global__ __launch_bounds__(256) void mfma_gemm(
    const short* __restrict__ XT, const short* __restrict__ Wb,
    void* __restrict__ Yv, const float* __restrict__ bias,
    const float* __restrict__ resid, int O, int Kp) {
  const int lane = threadIdx.x & 63;
  const int wid  = threadIdx.x >> 6;
  const int wl = wid & 1, wo = wid >> 1;
  const int bl = blockIdx.x * 128;
  const int bo = blockIdx.y * 64;
  const int g   = lane >> 4;
  const int r15 = lane & 15;

  f32x4 acc[4][2];
#pragma unroll
  for (int m = 0; m < 4; ++m)
#pragma unroll
    for (int n = 0; n < 2; ++n) acc[m][n] = (f32x4){0.f, 0.f, 0.f, 0.f};

  const short* xrow[4];
#pragma unroll
  for (int m = 0; m < 4; ++m)
    xrow[m] = XT + (size_t)(bl + wl * 64 + m * 16 + r15) * Kp + g * 8;
  const short* wrow[2];
#pragma unroll
  for (int n = 0; n < 2; ++n)
    wrow[n] = Wb + (size_t)(bo + wo * 32 + n * 16 + r15) * Kp + g * 8;

  for (int k0 = 0; k0 < Kp; k0 += 32) {
    ABFrag a[4], b[2];
#pragma unroll
    for (int m = 0; m < 4; ++m) a[m].q = *(const uint4*)(xrow[m] + k0);
#pragma unroll
    for (int n = 0; n < 2; ++n) b[n].q = *(const uint4*)(wrow[n] + k0);
#pragma unroll
    for (int m = 0; m < 4; ++m)
#pragma unroll
      for (int n = 0; n < 2; ++n)
        acc[m][n] = __builtin_amdgcn_mfma_f32_16x16x32_bf16(a[m].v, b[n].v,
                                                            acc[m][n], 0, 0, 0);
  }

  // epilogue: D col = o (lane&15), D row = pixel ((lane>>4)*4 + reg)
#pragma unroll
  for (int n = 0; n < 2; ++n) {
    int o = bo + wo * 32 + n * 16 + r15;
    if (o >= O) continue;
    float bv = HAS_BIAS ? bias[o] : 0.f;
#pragma unroll
    for (int m = 0; m < 4; ++m) {
      int l = bl + wl * 64 + m * 16 + (g << 2);
      f32x4 v = acc[m][n];
      if (HAS_BIAS) { v[0] += bv; v[1] += bv; v[2] += bv; v[3] += bv; }
      if (HAS_RESID) {
        const float4 r = *(const float4*)(resid + (size_t)o * L + l);
        v[0] += r.x; v[1] += r.y; v[2] += r.z; v[3] += r.w;
      }
      if (OUT_BF16) {
        uint2 s;
        s.x = (unsigned short)f2bf(v[0]) | ((unsigned)(unsigned short)f2bf(v[1]) << 16);
        s.y = (unsigned short)f2bf(v[2]) | ((unsigned)(unsigned short)f2bf(v[3]) << 16);
        *(uint2*)((short*)Yv + (size_t)o * L + l) = s;
      } else {
        *(float4*)((float*)Yv + (size_t)o * L + l) = make_float4(v[0], v[1], v[2], v[3]);
      }
    }
  }
}

// ------------------------------ LayerNorm ----------------------------------
// 4 waves split channels (32 each); 64 pixels per block; bf16 out XT[l][c].
__global__ __launch_bounds__(256) void ln_xt(const float* __restrict__ x,
                                             const float* __restrict__ w,
                                             const float* __restrict__ bias,
                                             short* __restrict__ yt) {
  const int lane = threadIdx.x & 63;
  const int wv   = threadIdx.x >> 6;      // wave 0..3 -> channels wv*32..+32
  const int l = blockIdx.x * 64 + lane;
  const float* xb = x + l;
  float vals[32];
  float s = 0.f, ss = 0.f;
#pragma unroll
  for (int j = 0; j < 32; ++j) {
    float v = xb[(size_t)(wv * 32 + j) * L];
    vals[j] = v; s += v; ss += v * v;
  }
  __shared__ float red[2][4][64];
  red[0][wv][lane] = s; red[1][wv][lane] = ss;
  __syncthreads();
  float s4 = red[0][0][lane] + red[0][1][lane] + red[0][2][lane] + red[0][3][lane];
  float q4 = red[1][0][lane] + red[1][1][lane] + red[1][2][lane] + red[1][3][lane];
  float mu = s4 * (1.f / C);
  float var = q4 * (1.f / C) - mu * mu;
  float rstd = rsqrtf(var + 1e-5f);
  short* yr = yt + (size_t)l * C + wv * 32;
#pragma unroll
  for (int c0 = 0; c0 < 32; c0 += 8) {
    U4S8 u;
#pragma unroll
    for (int j = 0; j < 8; ++j)
      u.s[j] = f2bf((vals[c0 + j] - mu) * rstd * w[wv * 32 + c0 + j] + bias[wv * 32 + c0 + j]);
    *(uint4*)(yr + c0) = u.q;
  }
}

// ------------------------- lepe: depthwise 5x5 -----------------------------
// Stripe: 8 rows x 128 cols, 2 channels/block. Coalesced float4 loads.
__global__ __launch_bounds__(256) void dw5_kernel(const float* __restrict__ qkvo,
                                                  const float* __restrict__ wdw,
                                                  const float* __restrict__ bdw,
                                                  float* __restrict__ outb) {
  const int ty0 = blockIdx.x * 8;      // 16 row tiles
  const int c0  = blockIdx.y * 2;      // 64 channel pairs
  __shared__ float t[2][12][128];
  __shared__ float wc[2][25];
  const int tid = threadIdx.x;
  if (tid < 50) wc[tid / 25][tid % 25] = wdw[(c0 + tid / 25) * 25 + tid % 25];
  for (int idx = tid; idx < 768; idx += 256) {
    int q = idx & 31, u = idx >> 5;
    int row = u % 12, ch = u / 12;
    int gy = ty0 + row - 2;
    float4 v = make_float4(0.f, 0.f, 0.f, 0.f);
    if (gy >= 0 && gy < 128)
      v = *(const float4*)(qkvo + (size_t)(256 + c0 + ch) * L + gy * 128 + q * 4);
    *(float4*)&t[ch][row][q * 4] = v;
  }
  __syncthreads();
  const int r = tid >> 5, cg = (tid & 31) * 4;
#pragma unroll
  for (int ch = 0; ch < 2; ++ch) {
    float acc[4] = {0.f, 0.f, 0.f, 0.f};
#pragma unroll
    for (int i = 0; i < 5; ++i) {
      const float* row = &t[ch][r + i][0];
      float v[8];
      v[0] = (cg - 2 >= 0)   ? row[cg - 2] : 0.f;
      v[1] = (cg - 1 >= 0)   ? row[cg - 1] : 0.f;
      float4 m = *(const float4*)&row[cg];
      v[2] = m.x; v[3] = m.y; v[4] = m.z; v[5] = m.w;
      v[6] = (cg + 4 < 128) ? row[cg + 4] : 0.f;
      v[7] = (cg + 5 < 128) ? row[cg + 5] : 0.f;
#pragma unroll
      for (int cc = 0; cc < 4; ++cc)
#pragma unroll
        for (int j = 0; j < 5; ++j)
          acc[cc] = fmaf(v[cc + j], wc[ch][i * 5 + j], acc[cc]);
    }
    float bv = bdw[c0 + ch];
    float4 o = make_float4(acc[0] + bv, acc[1] + bv, acc[2] + bv, acc[3] + bv);
    *(float4*)(outb + (size_t)(c0 + ch) * L + (ty0 + r) * 128 + cg) = o;
  }
}

__device__ inline void theta_shift8(const float* x, const float* sn,
                                    const float* cs, float* o) {
#pragma unroll
  for (int i = 0; i < 4; ++i) {
    float x0 = x[2 * i], x1 = x[2 * i + 1];
    o[2 * i]     = x0 * cs[2 * i]     - x1 * sn[2 * i];
    o[2 * i + 1] = x1 * cs[2 * i + 1] + x0 * sn[2 * i + 1];
  }
}

// rope table: sin/cos of i and i*1e-4 for i in [0,128)
#define ROPE_TABLE_DECL \
  __shared__ float ts0[128], ts4[128], tc0[128], tc4[128];
#define ROPE_TABLE_FILL(tid) \
  if ((tid) < 128) { \
    float s_, c_; \
    sincosf((float)(tid), &s_, &c_); ts0[tid] = s_; tc0[tid] = c_; \
    sincosf((float)(tid) * 1e-4f, &s_, &c_); ts4[tid] = s_; tc4[tid] = c_; \
  }
#define ROPE_LOOKUP(l, sn, cs) { \
    int h_ = (l) >> 7, w_ = (l) & 127; \
    sn[0] = sn[1] = ts0[h_]; sn[2] = sn[3] = ts4[h_]; \
    sn[4] = sn[5] = ts0[w_]; sn[6] = sn[7] = ts4[w_]; \
    cs[0] = cs[1] = tc0[h_]; cs[2] = cs[3] = tc4[h_]; \
    cs[4] = cs[5] = tc0[w_]; cs[6] = cs[7] = tc4[w_]; }

// ------------------- per-head kv / mean_k / mean_v sums --------------------
__global__ __launch_bounds__(256) void kvstats_kernel(const float* __restrict__ qkvo,
                                                      float* __restrict__ stats) {
  int n = blockIdx.y;                 // head 0..15
  int l0 = blockIdx.x * 512;
  int tid = threadIdx.x;
  ROPE_TABLE_DECL
  ROPE_TABLE_FILL(tid)
  __syncthreads();
  const float* kb = qkvo + (size_t)(128 + n * 8) * L;
  const float* vb = qkvo + (size_t)(256 + n * 8) * L;
  float kv[8][8] = {};
  float mk[8] = {}, mv[8] = {};
  for (int l = l0 + tid; l < l0 + 512; l += 256) {
    float sn[8], cs[8];
    ROPE_LOOKUP(l, sn, cs)
    float ke[8], kt[8], vv[8];
#pragma unroll
    for (int d = 0; d < 8; ++d) {
      float kval = kb[(size_t)d * L + l];
      ke[d] = kval > 0.f ? kval + 1.f : expf(kval);
      mk[d] += ke[d];
      vv[d] = vb[(size_t)d * L + l];
      mv[d] += vv[d];
    }
    theta_shift8(ke, sn, cs, kt);
#pragma unroll
    for (int d = 0; d < 8; ++d)
#pragma unroll
      for (int e = 0; e < 8; ++e) kv[d][e] = fmaf(kt[d], vv[e], kv[d][e]);
  }
  float valsr[80];
#pragma unroll
  for (int d = 0; d < 8; ++d)
#pragma unroll
    for (int e = 0; e < 8; ++e) valsr[d * 8 + e] = kv[d][e];
#pragma unroll
  for (int d = 0; d < 8; ++d) { valsr[64 + d] = mk[d]; valsr[72 + d] = mv[d]; }
#pragma unroll
  for (int i = 0; i < 80; ++i) {
    float v = valsr[i];
#pragma unroll
    for (int off = 32; off > 0; off >>= 1) v += __shfl_down(v, off);
    valsr[i] = v;
  }
  __shared__ float red[4][80];
  int lane = tid & 63, wid = tid >> 6;
  if (lane == 0) {
#pragma unroll
    for (int i = 0; i < 80; ++i) red[wid][i] = valsr[i];
  }
  __syncthreads();
  if (tid < 80) {
    float s2 = red[0][tid] + red[1][tid] + red[2][tid] + red[3][tid];
    atomicAdd(&stats[n * 80 + tid], s2);
  }
}

// --- attn mix: res = q~·kv*(1+1/z) - z*mean_v; XT out = (res+lepe)*o_gate ---
__global__ __launch_bounds__(256) void attnmix_kernel(const float* __restrict__ qkvo,
                                                      const float* __restrict__ lepe,
                                                      const float* __restrict__ stats,
                                                      short* __restrict__ outt) {
  int n = blockIdx.y;                 // head 0..15
  int tid = threadIdx.x;
  ROPE_TABLE_DECL
  __shared__ float kvs[64], mks[8], mvs[8];
  ROPE_TABLE_FILL(tid)
  else if (tid < 192)     kvs[tid - 128] = stats[n * 80 + tid - 128] * (SCALE / (float)L);
  else if (tid < 200)  mks[tid - 192] = stats[n * 80 + tid - 128] * (1.f / (float)L);
  else if (tid < 208)  mvs[tid - 200] = stats[n * 80 + tid - 128] * (1.f / (float)L);
  __syncthreads();
  int l = blockIdx.x * 256 + tid;
  const float* qb = qkvo + (size_t)(n * 8) * L + l;
  const float* ob = qkvo + (size_t)(384 + n * 8) * L + l;
  const float* lb = lepe + (size_t)(n * 8) * L + l;
  float qe[8];
#pragma unroll
  for (int d = 0; d < 8; ++d) {
    float qv = qb[(size_t)d * L];
    qe[d] = qv > 0.f ? qv + 1.f : expf(qv);
  }
  float z = 0.f;
#pragma unroll
  for (int d = 0; d < 8; ++d) z += qe[d] * mks[d];
  z *= SCALE;
  float sn[8], cs[8];
  ROPE_LOOKUP(l, sn, cs)
  float qt[8];
  theta_shift8(qe, sn, cs, qt);
  float coef = 1.f + 1.f / (z + 1e-6f);
  U4S8 u;
#pragma unroll
  for (int e = 0; e < 8; ++e) {
    float r = 0.f;
#pragma unroll
    for (int d = 0; d < 8; ++d) r = fmaf(qt[d], kvs[d * 8 + e], r);
    float res = r * coef - z * mvs[e];
    u.s[e] = f2bf((res + lb[(size_t)e * L]) * ob[(size_t)e * L]);
  }
  *(uint4*)(outt + (size_t)l * C + n * 8) = u.q;   // XT[l][n*8..n*8+8)
}

// ---------------- FFN: depthwise 3x3 + GELU gate -> XT[l][352] -------------
// Stripe: 8 rows x 128 cols; 8 output channels (both halves) per block.
__global__ __launch_bounds__(256) void dw3gate_kernel(const short* __restrict__ p,
                                                      const float* __restrict__ wdw,
                                                      short* __restrict__ gxt) {
  const int ty0 = blockIdx.x * 8;      // 16 row tiles
  const int c0  = blockIdx.y * 8;      // 44 chunks (incl. zero pad 340..351)
  __shared__ short tile[16][10][128];  // [half*8+ch][row][col], 40KB
  __shared__ float wa[8][9], wb[8][9];
  const int tid = threadIdx.x;
  if (tid < 144) {
    int ch = tid / 9, j = tid % 9;
    int half = ch >> 3, cc = c0 + (ch & 7);
    float wv = (cc < 340) ? wdw[(half * 340 + cc) * 9 + j] : 0.f;
    if (half) wb[ch & 7][j] = wv; else wa[ch & 7][j] = wv;
  }
  for (int idx = tid; idx < 2560; idx += 256) {
    int q = idx & 15, u = idx >> 4;
    int row = u % 10, chh = u / 10;       // chh: 0..15
    int cc = c0 + (chh & 7), half = chh >> 3;
    int gy = ty0 + row - 1;
    uint4 v = make_uint4(0u, 0u, 0u, 0u);
    if (cc < 340 && gy >= 0 && gy < 128)
      v = *(const uint4*)(p + (size_t)(half * 340 + cc) * L + gy * 128 + q * 8);
    *(uint4*)&tile[chh][row][q * 8] = v;
  }
  __syncthreads();
  const int r = tid >> 5, cg = (tid & 31) * 4;
  U4S8 ou[4];
#pragma unroll
  for (int ch = 0; ch < 8; ++ch) {
    float accA[4] = {0.f, 0.f, 0.f, 0.f};
    float accB[4] = {0.f, 0.f, 0.f, 0.f};
#pragma unroll
    for (int half = 0; half < 2; ++half) {
      float* acc = half ? accB : accA;
      const float* wt = half ? wb[ch] : wa[ch];
#pragma unroll
      for (int i = 0; i < 3; ++i) {
        const short* row = &tile[half * 8 + ch][r + i][0];
        float v[6];
        v[0] = (cg - 1 >= 0) ? bf2f(row[cg - 1]) : 0.f;
        U2S4 m; m.q = *(const uint2*)&row[cg];
        v[1] = bf2f(m.s[0]); v[2] = bf2f(m.s[1]);
        v[3] = bf2f(m.s[2]); v[4] = bf2f(m.s[3]);
        v[5] = (cg + 4 < 128) ? bf2f(row[cg + 4]) : 0.f;
#pragma unroll
        for (int cc = 0; cc < 4; ++cc)
#pragma unroll
          for (int j = 0; j < 3; ++j)
            acc[cc] = fmaf(v[cc + j], wt[i * 3 + j], acc[cc]);
      }
    }
#pragma unroll
    for (int cc = 0; cc < 4; ++cc) {
      float a = accA[cc];
      float ge = 0.5f * a * (1.f + erff(a * 0.70710678f));
      ou[cc].s[ch] = f2bf(ge * accB[cc]);
    }
  }
#pragma unroll
  for (int cc = 0; cc < 4; ++cc) {
    int pix = (ty0 + r) * 128 + cg + cc;
    *(uint4*)(gxt + (size_t)pix * 352 + c0) = ou[cc].q;
  }
}

// ---------------------------------------------------------------------------
extern "C" void kernel_launch(void* const* d_in, const int* in_sizes, int n_in,
                              void* d_out, int out_size, void* d_ws, size_t ws_size,
                              hipStream_t stream) {
  const float* x        = (const float*)d_in[0];
  const float* ln1_w    = (const float*)d_in[1];
  const float* ln1_b    = (const float*)d_in[2];
  const float* qkvo_w   = (const float*)d_in[3];
  const float* qkvo_b   = (const float*)d_in[4];
  const float* lepe_w   = (const float*)d_in[5];
  const float* lepe_b   = (const float*)d_in[6];
  const float* proj_w   = (const float*)d_in[7];
  const float* proj_b   = (const float*)d_in[8];
  const float* ln2_w    = (const float*)d_in[9];
  const float* ln2_b    = (const float*)d_in[10];
  const float* ffn_in_w = (const float*)d_in[11];
  const float* ffn_dw_w = (const float*)d_in[12];
  const float* ffn_out_w= (const float*)d_in[13];
  float* out = (float*)d_out;

  // workspace layout (bytes)
  const size_t QKVO_OFF = 0;              // 33,554,432 fp32 [512][L]
  const size_t XN_OFF   = 33554432ull;    //  4,194,304 bf16 XT [L][128]
  const size_t LEPE_OFF = 37748736ull;    //  8,388,608 fp32 [128][L]
  const size_t P_OFF    = 46137344ull;    // 22,282,240 bf16 [680][L]
  const size_t G_OFF    = 68419584ull;    // 11,534,336 bf16 XT [L][352]
  const size_t STAT_OFF = 79953920ull;    //     40,960 fp32 [8][16][80]
  const size_t WQ_OFF   = 79994880ull;    //    131,072 bf16 [512][128]
  const size_t WP_OFF   = 80125952ull;    //     32,768 bf16 [128][128]
  const size_t WFI_OFF  = 80158720ull;    //    174,080 bf16 [680][128]
  const size_t WFO_OFF  = 80332800ull;    //     90,112 bf16 [128][352]
  const size_t NEEDED   = 80422912ull;
  if (ws_size < NEEDED) return;

  char* ws = (char*)d_ws;
  float* qbuf  = (float*)(ws + QKVO_OFF);
  short* xnbuf = (short*)(ws + XN_OFF);
  float* lepeb = (float*)(ws + LEPE_OFF);
  short* pbuf  = (short*)(ws + P_OFF);
  short* gxt   = (short*)(ws + G_OFF);
  float* stats = (float*)(ws + STAT_OFF);
  short* wq    = (short*)(ws + WQ_OFF);
  short* wp    = (short*)(ws + WP_OFF);
  short* wfi   = (short*)(ws + WFI_OFF);
  short* wfo   = (short*)(ws + WFO_OFF);

  convert_w<<<dim3((512 * 128 + 255) / 256), 256, 0, stream>>>(qkvo_w, wq, 512, 128, 128);
  convert_w<<<dim3((128 * 128 + 255) / 256), 256, 0, stream>>>(proj_w, wp, 128, 128, 128);
  convert_w<<<dim3((680 * 128 + 255) / 256), 256, 0, stream>>>(ffn_in_w, wfi, 680, 128, 128);
  convert_w<<<dim3((128 * 352 + 255) / 256), 256, 0, stream>>>(ffn_out_w, wfo, 128, 340, 352);
  hipMemsetAsync(stats, 0, 128 * 80 * sizeof(float), stream);

  for (int b = 0; b < BN; ++b) {
    const float* xb   = x   + (size_t)b * C * L;
    float*       outb = out + (size_t)b * C * L;
    float*       st_b = stats + (size_t)b * 16 * 80;

    // K1: LN1 -> xn XT (bf16)
    ln_xt<<<dim3(256), 256, 0, stream>>>(xb, ln1_w, ln1_b, xnbuf);
    // K2: qkvo GEMM (O=512, K=128) -> qbuf fp32 [512][L]
    mfma_gemm<0, 1, 0><<<dim3(128, 8), 256, 0, stream>>>(xnbuf, wq, qbuf,
                                                         qkvo_b, nullptr, 512, 128);
    // K3: lepe dwconv 5x5 on v -> lepe fp32
    dw5_kernel<<<dim3(16, 64), 256, 0, stream>>>(qbuf, lepe_w, lepe_b, lepeb);
    // K4: per-head stats
    kvstats_kernel<<<dim3(32, 16), 256, 0, stream>>>(qbuf, st_b);
    // K5: attention mix -> attn_in XT (bf16, reuse XN)
    attnmix_kernel<<<dim3(64, 16), 256, 0, stream>>>(qbuf, lepeb, st_b, xnbuf);
    // K6: proj GEMM + bias + residual x -> out (fp32 x1)
    mfma_gemm<0, 1, 1><<<dim3(128, 2), 256, 0, stream>>>(xnbuf, wp, outb,
                                                         proj_b, xb, 128, 128);
    // K7: LN2 -> xn2 XT (bf16, reuse XN)
    ln_xt<<<dim3(256), 256, 0, stream>>>(outb, ln2_w, ln2_b, xnbuf);
    // K8: ffn_in GEMM (O=680, K=128) -> p (bf16 [680][L])
    mfma_gemm<1, 0, 0><<<dim3(128, 11), 256, 0, stream>>>(xnbuf, wfi, pbuf,
                                                          nullptr, nullptr, 680, 128);
    // K9: dwconv3x3 + GELU gate -> g XT [L][352] (pad chunks write zeros)
    dw3gate_kernel<<<dim3(16, 44), 256, 0, stream>>>(pbuf, ffn_dw_w, gxt);
    // K10: ffn_out GEMM (O=128, Kp=352) + residual x1 -> out (in place)
    mfma_gemm<0, 0, 1><<<dim3(128, 2), 256, 0, stream>>>(gxt, wfo, outb,
                                                         nullptr, outb, 128, 352);
  }
}

// Round 6
// 1052.761 us; speedup vs baseline: 1.7430x; 1.2031x over previous
//
#include <hip/hip_runtime.h>

// ---------------------------------------------------------------------------
// TransformerBlock (linear attention + FFN) on MI355X — bf16 MFMA GEMMs,
// LDS-free GEMM reading pre-transposed activations XT[pixel][c].
// R5: qkvo output bf16; dw3gate 4-ch chunks (occupancy); kvstats 4px/thread.
// ---------------------------------------------------------------------------

static constexpr int C   = 128;
static constexpr int L   = 16384;   // 128*128
static constexpr int BN  = 8;       // batch
static constexpr float SCALE = 0.35355339f;  // 1/sqrt(8)

typedef short bf16x8 __attribute__((ext_vector_type(8)));
typedef float f32x4  __attribute__((ext_vector_type(4)));

union ABFrag { bf16x8 v; uint4 q; };
union U4S8   { uint4 q; short s[8]; };
union U2S4   { uint2 q; short s[4]; };

__device__ inline short f2bf(float f) {
  unsigned u = __float_as_uint(f);
  u += 0x7FFFu + ((u >> 16) & 1u);
  return (short)(u >> 16);
}
__device__ inline float bf2f(short s) {
  return __uint_as_float(((unsigned)(unsigned short)s) << 16);
}

// ------------------------- weight fp32 -> bf16 (K-pad) ---------------------
__global__ __launch_bounds__(256) void convert_w(const float* __restrict__ src,
                                                 short* __restrict__ dst,
                                                 int O, int K, int Kp) {
  int idx = blockIdx.x * 256 + threadIdx.x;
  if (idx >= O * Kp) return;
  int o = idx / Kp, k = idx - o * Kp;
  dst[idx] = (k < K) ? f2bf(src[o * K + k]) : (short)0;
}

// ------------------------------ MFMA GEMM ----------------------------------
// Y[o][l] = sum_k W[o][k] * XT[l][k]  (+bias) (+resid). No LDS.
// Block tile: 128 l x 64 o, 4 waves (2l x 2o), wave = 64l x 32o, BK=32.
template <int OUT_BF16, int HAS_BIAS, int HAS_RESID>
__global__ __launch_bounds__(256) void mfma_gemm(
    const short* __restrict__ XT, const short* __restrict__ Wb,
    void* __restrict__ Yv, const float* __restrict__ bias,
    const float* __restrict__ resid, int O, int Kp) {
  const int lane = threadIdx.x & 63;
  const int wid  = threadIdx.x >> 6;
  const int wl = wid & 1, wo = wid >> 1;
  const int bl = blockIdx.x * 128;
  const int bo = blockIdx.y * 64;
  const int g   = lane >> 4;
  const int r15 = lane & 15;

  f32x4 acc[4][2];
#pragma unroll
  for (int m = 0; m < 4; ++m)
#pragma unroll
    for (int n = 0; n < 2; ++n) acc[m][n] = (f32x4){0.f, 0.f, 0.f, 0.f};

  const short* xrow[4];
#pragma unroll
  for (int m = 0; m < 4; ++m)
    xrow[m] = XT + (size_t)(bl + wl * 64 + m * 16 + r15) * Kp + g * 8;
  const short* wrow[2];
#pragma unroll
  for (int n = 0; n < 2; ++n)
    wrow[n] = Wb + (size_t)(bo + wo * 32 + n * 16 + r15) * Kp + g * 8;

  for (int k0 = 0; k0 < Kp; k0 += 32) {
    ABFrag a[4], b[2];
#pragma unroll
    for (int m = 0; m < 4; ++m) a[m].q = *(const uint4*)(xrow[m] + k0);
#pragma unroll
    for (int n = 0; n < 2; ++n) b[n].q = *(const uint4*)(wrow[n] + k0);
#pragma unroll
    for (int m = 0; m < 4; ++m)
#pragma unroll
      for (int n = 0; n < 2; ++n)
        acc[m][n] = __builtin_amdgcn_mfma_f32_16x16x32_bf16(a[m].v, b[n].v,
                                                            acc[m][n], 0, 0, 0);
  }

  // epilogue: D col = o (lane&15), D row = pixel ((lane>>4)*4 + reg)
#pragma unroll
  for (int n = 0; n < 2; ++n) {
    int o = bo + wo * 32 + n * 16 + r15;
    if (o >= O) continue;
    float bv = HAS_BIAS ? bias[o] : 0.f;
#pragma unroll
    for (int m = 0; m < 4; ++m) {
      int l = bl + wl * 64 + m * 16 + (g << 2);
      f32x4 v = acc[m][n];
      if (HAS_BIAS) { v[0] += bv; v[1] += bv; v[2] += bv; v[3] += bv; }
      if (HAS_RESID) {
        const float4 r = *(const float4*)(resid + (size_t)o * L + l);
        v[0] += r.x; v[1] += r.y; v[2] += r.z; v[3] += r.w;
      }
      if (OUT_BF16) {
        uint2 s;
        s.x = (unsigned short)f2bf(v[0]) | ((unsigned)(unsigned short)f2bf(v[1]) << 16);
        s.y = (unsigned short)f2bf(v[2]) | ((unsigned)(unsigned short)f2bf(v[3]) << 16);
        *(uint2*)((short*)Yv + (size_t)o * L + l) = s;
      } else {
        *(float4*)((float*)Yv + (size_t)o * L + l) = make_float4(v[0], v[1], v[2], v[3]);
      }
    }
  }
}

// ------------------------------ LayerNorm ----------------------------------
// 4 waves split channels (32 each); 64 pixels per block; bf16 out XT[l][c].
__global__ __launch_bounds__(256) void ln_xt(const float* __restrict__ x,
                                             const float* __restrict__ w,
                                             const float* __restrict__ bias,
                                             short* __restrict__ yt) {
  const int lane = threadIdx.x & 63;
  const int wv   = threadIdx.x >> 6;      // wave 0..3 -> channels wv*32..+32
  const int l = blockIdx.x * 64 + lane;
  const float* xb = x + l;
  float vals[32];
  float s = 0.f, ss = 0.f;
#pragma unroll
  for (int j = 0; j < 32; ++j) {
    float v = xb[(size_t)(wv * 32 + j) * L];
    vals[j] = v; s += v; ss += v * v;
  }
  __shared__ float red[2][4][64];
  red[0][wv][lane] = s; red[1][wv][lane] = ss;
  __syncthreads();
  float s4 = red[0][0][lane] + red[0][1][lane] + red[0][2][lane] + red[0][3][lane];
  float q4 = red[1][0][lane] + red[1][1][lane] + red[1][2][lane] + red[1][3][lane];
  float mu = s4 * (1.f / C);
  float var = q4 * (1.f / C) - mu * mu;
  float rstd = rsqrtf(var + 1e-5f);
  short* yr = yt + (size_t)l * C + wv * 32;
#pragma unroll
  for (int c0 = 0; c0 < 32; c0 += 8) {
    U4S8 u;
#pragma unroll
    for (int j = 0; j < 8; ++j)
      u.s[j] = f2bf((vals[c0 + j] - mu) * rstd * w[wv * 32 + c0 + j] + bias[wv * 32 + c0 + j]);
    *(uint4*)(yr + c0) = u.q;
  }
}

// ------------------------- lepe: depthwise 5x5 (bf16 in) -------------------
// Stripe: 8 rows x 128 cols, 2 channels/block. Coalesced uint4 loads.
__global__ __launch_bounds__(256) void dw5_kernel(const short* __restrict__ qkvo,
                                                  const float* __restrict__ wdw,
                                                  const float* __restrict__ bdw,
                                                  float* __restrict__ outb) {
  const int ty0 = blockIdx.x * 8;      // 16 row tiles
  const int c0  = blockIdx.y * 2;      // 64 channel pairs
  __shared__ float t[2][12][128];
  __shared__ float wc[2][25];
  const int tid = threadIdx.x;
  if (tid < 50) wc[tid / 25][tid % 25] = wdw[(c0 + tid / 25) * 25 + tid % 25];
  for (int idx = tid; idx < 384; idx += 256) {
    int q = idx & 15, u = idx >> 4;
    int row = u % 12, ch = u / 12;
    int gy = ty0 + row - 2;
    U4S8 v; v.q = make_uint4(0u, 0u, 0u, 0u);
    if (gy >= 0 && gy < 128)
      v.q = *(const uint4*)(qkvo + (size_t)(256 + c0 + ch) * L + gy * 128 + q * 8);
    float4 lo = make_float4(bf2f(v.s[0]), bf2f(v.s[1]), bf2f(v.s[2]), bf2f(v.s[3]));
    float4 hi = make_float4(bf2f(v.s[4]), bf2f(v.s[5]), bf2f(v.s[6]), bf2f(v.s[7]));
    *(float4*)&t[ch][row][q * 8] = lo;
    *(float4*)&t[ch][row][q * 8 + 4] = hi;
  }
  __syncthreads();
  const int r = tid >> 5, cg = (tid & 31) * 4;
#pragma unroll
  for (int ch = 0; ch < 2; ++ch) {
    float acc[4] = {0.f, 0.f, 0.f, 0.f};
#pragma unroll
    for (int i = 0; i < 5; ++i) {
      const float* row = &t[ch][r + i][0];
      float v[8];
      v[0] = (cg - 2 >= 0)   ? row[cg - 2] : 0.f;
      v[1] = (cg - 1 >= 0)   ? row[cg - 1] : 0.f;
      float4 m = *(const float4*)&row[cg];
      v[2] = m.x; v[3] = m.y; v[4] = m.z; v[5] = m.w;
      v[6] = (cg + 4 < 128) ? row[cg + 4] : 0.f;
      v[7] = (cg + 5 < 128) ? row[cg + 5] : 0.f;
#pragma unroll
      for (int cc = 0; cc < 4; ++cc)
#pragma unroll
        for (int j = 0; j < 5; ++j)
          acc[cc] = fmaf(v[cc + j], wc[ch][i * 5 + j], acc[cc]);
    }
    float bv = bdw[c0 + ch];
    float4 o = make_float4(acc[0] + bv, acc[1] + bv, acc[2] + bv, acc[3] + bv);
    *(float4*)(outb + (size_t)(c0 + ch) * L + (ty0 + r) * 128 + cg) = o;
  }
}

__device__ inline void theta_shift8(const float* x, const float* sn,
                                    const float* cs, float* o) {
#pragma unroll
  for (int i = 0; i < 4; ++i) {
    float x0 = x[2 * i], x1 = x[2 * i + 1];
    o[2 * i]     = x0 * cs[2 * i]     - x1 * sn[2 * i];
    o[2 * i + 1] = x1 * cs[2 * i + 1] + x0 * sn[2 * i + 1];
  }
}

// rope table: sin/cos of i and i*1e-4 for i in [0,128)
#define ROPE_TABLE_DECL \
  __shared__ float ts0[128], ts4[128], tc0[128], tc4[128];
#define ROPE_TABLE_FILL(tid) \
  if ((tid) < 128) { \
    float s_, c_; \
    sincosf((float)(tid), &s_, &c_); ts0[tid] = s_; tc0[tid] = c_; \
    sincosf((float)(tid) * 1e-4f, &s_, &c_); ts4[tid] = s_; tc4[tid] = c_; \
  }
#define ROPE_LOOKUP(l, sn, cs) { \
    int h_ = (l) >> 7, w_ = (l) & 127; \
    sn[0] = sn[1] = ts0[h_]; sn[2] = sn[3] = ts4[h_]; \
    sn[4] = sn[5] = ts0[w_]; sn[6] = sn[7] = ts4[w_]; \
    cs[0] = cs[1] = tc0[h_]; cs[2] = cs[3] = tc4[h_]; \
    cs[4] = cs[5] = tc0[w_]; cs[6] = cs[7] = tc4[w_]; }

// ------------------- per-head kv / mean_k / mean_v sums --------------------
// grid (16 l-chunks of 1024, 16 heads); 4 px/thread amortizes the reduce.
__global__ __launch_bounds__(256) void kvstats_kernel(const short* __restrict__ qkvo,
                                                      float* __restrict__ stats) {
  int n = blockIdx.y;                 // head 0..15
  int l0 = blockIdx.x * 1024;
  int tid = threadIdx.x;
  ROPE_TABLE_DECL
  ROPE_TABLE_FILL(tid)
  __syncthreads();
  const short* kb = qkvo + (size_t)(128 + n * 8) * L;
  const short* vb = qkvo + (size_t)(256 + n * 8) * L;
  float kv[8][8] = {};
  float mk[8] = {}, mv[8] = {};
  for (int l = l0 + tid; l < l0 + 1024; l += 256) {
    float sn[8], cs[8];
    ROPE_LOOKUP(l, sn, cs)
    float ke[8], kt[8], vv[8];
#pragma unroll
    for (int d = 0; d < 8; ++d) {
      float kval = bf2f(kb[(size_t)d * L + l]);
      ke[d] = kval > 0.f ? kval + 1.f : expf(kval);
      mk[d] += ke[d];
      vv[d] = bf2f(vb[(size_t)d * L + l]);
      mv[d] += vv[d];
    }
    theta_shift8(ke, sn, cs, kt);
#pragma unroll
    for (int d = 0; d < 8; ++d)
#pragma unroll
      for (int e = 0; e < 8; ++e) kv[d][e] = fmaf(kt[d], vv[e], kv[d][e]);
  }
  float valsr[80];
#pragma unroll
  for (int d = 0; d < 8; ++d)
#pragma unroll
    for (int e = 0; e < 8; ++e) valsr[d * 8 + e] = kv[d][e];
#pragma unroll
  for (int d = 0; d < 8; ++d) { valsr[64 + d] = mk[d]; valsr[72 + d] = mv[d]; }
#pragma unroll
  for (int i = 0; i < 80; ++i) {
    float v = valsr[i];
#pragma unroll
    for (int off = 32; off > 0; off >>= 1) v += __shfl_down(v, off);
    valsr[i] = v;
  }
  __shared__ float red[4][80];
  int lane = tid & 63, wid = tid >> 6;
  if (lane == 0) {
#pragma unroll
    for (int i = 0; i < 80; ++i) red[wid][i] = valsr[i];
  }
  __syncthreads();
  if (tid < 80) {
    float s2 = red[0][tid] + red[1][tid] + red[2][tid] + red[3][tid];
    atomicAdd(&stats[n * 80 + tid], s2);
  }
}

// --- attn mix: res = q~·kv*(1+1/z) - z*mean_v; XT out = (res+lepe)*o_gate ---
__global__ __launch_bounds__(256) void attnmix_kernel(const short* __restrict__ qkvo,
                                                      const float* __restrict__ lepe,
                                                      const float* __restrict__ stats,
                                                      short* __restrict__ outt) {
  int n = blockIdx.y;                 // head 0..15
  int tid = threadIdx.x;
  ROPE_TABLE_DECL
  __shared__ float kvs[64], mks[8], mvs[8];
  ROPE_TABLE_FILL(tid)
  else if (tid < 192)  kvs[tid - 128] = stats[n * 80 + tid - 128] * (SCALE / (float)L);
  else if (tid < 200)  mks[tid - 192] = stats[n * 80 + tid - 128] * (1.f / (float)L);
  else if (tid < 208)  mvs[tid - 200] = stats[n * 80 + tid - 128] * (1.f / (float)L);
  __syncthreads();
  int l = blockIdx.x * 256 + tid;
  const short* qb = qkvo + (size_t)(n * 8) * L + l;
  const short* ob = qkvo + (size_t)(384 + n * 8) * L + l;
  const float* lb = lepe + (size_t)(n * 8) * L + l;
  float qe[8];
#pragma unroll
  for (int d = 0; d < 8; ++d) {
    float qv = bf2f(qb[(size_t)d * L]);
    qe[d] = qv > 0.f ? qv + 1.f : expf(qv);
  }
  float z = 0.f;
#pragma unroll
  for (int d = 0; d < 8; ++d) z += qe[d] * mks[d];
  z *= SCALE;
  float sn[8], cs[8];
  ROPE_LOOKUP(l, sn, cs)
  float qt[8];
  theta_shift8(qe, sn, cs, qt);
  float coef = 1.f + 1.f / (z + 1e-6f);
  U4S8 u;
#pragma unroll
  for (int e = 0; e < 8; ++e) {
    float r = 0.f;
#pragma unroll
    for (int d = 0; d < 8; ++d) r = fmaf(qt[d], kvs[d * 8 + e], r);
    float res = r * coef - z * mvs[e];
    u.s[e] = f2bf((res + lb[(size_t)e * L]) * bf2f(ob[(size_t)e * L]));
  }
  *(uint4*)(outt + (size_t)l * C + n * 8) = u.q;   // XT[l][n*8..n*8+8)
}

// ---------------- FFN: depthwise 3x3 + GELU gate -> XT[l][352] -------------
// Stripe: 8 rows x 128 cols; 4 output channels (both halves) per block.
// LDS ~21KB -> 7 blocks/CU; grid (16,88)=1408 blocks.
__global__ __launch_bounds__(256) void dw3gate_kernel(const short* __restrict__ p,
                                                      const float* __restrict__ wdw,
                                                      short* __restrict__ gxt) {
  const int ty0 = blockIdx.x * 8;      // 16 row tiles
  const int c0  = blockIdx.y * 4;      // 88 chunks (incl. zero pad 340..351)
  __shared__ short tile[8][10][128];   // slot = half*4+ch, 20KB
  __shared__ float wt[8][9];
  const int tid = threadIdx.x;
  if (tid < 72) {
    int slot = tid / 9, j = tid % 9;
    int half = slot >> 2, cc = c0 + (slot & 3);
    wt[slot][j] = (cc < 340) ? wdw[(half * 340 + cc) * 9 + j] : 0.f;
  }
  for (int idx = tid; idx < 1280; idx += 256) {
    int q = idx & 15, u = idx >> 4;       // u: 0..79
    int row = u % 10, slot = u / 10;      // slot: 0..7
    int cc = c0 + (slot & 3), half = slot >> 2;
    int gy = ty0 + row - 1;
    uint4 v = make_uint4(0u, 0u, 0u, 0u);
    if (cc < 340 && gy >= 0 && gy < 128)
      v = *(const uint4*)(p + (size_t)(half * 340 + cc) * L + gy * 128 + q * 8);
    *(uint4*)&tile[slot][row][q * 8] = v;
  }
  __syncthreads();
  const int r = tid >> 5, cg = (tid & 31) * 4;
  U2S4 ou[4];
#pragma unroll
  for (int ch = 0; ch < 4; ++ch) {
    float accA[4] = {0.f, 0.f, 0.f, 0.f};
    float accB[4] = {0.f, 0.f, 0.f, 0.f};
#pragma unroll
    for (int half = 0; half < 2; ++half) {
      float* acc = half ? accB : accA;
      const float* w9 = wt[half * 4 + ch];
#pragma unroll
      for (int i = 0; i < 3; ++i) {
        const short* row = &tile[half * 4 + ch][r + i][0];
        float v[6];
        v[0] = (cg - 1 >= 0) ? bf2f(row[cg - 1]) : 0.f;
        U2S4 m; m.q = *(const uint2*)&row[cg];
        v[1] = bf2f(m.s[0]); v[2] = bf2f(m.s[1]);
        v[3] = bf2f(m.s[2]); v[4] = bf2f(m.s[3]);
        v[5] = (cg + 4 < 128) ? bf2f(row[cg + 4]) : 0.f;
#pragma unroll
        for (int cc = 0; cc < 4; ++cc)
#pragma unroll
          for (int j = 0; j < 3; ++j)
            acc[cc] = fmaf(v[cc + j], w9[i * 3 + j], acc[cc]);
      }
    }
#pragma unroll
    for (int cc = 0; cc < 4; ++cc) {
      float a = accA[cc];
      float ge = 0.5f * a * (1.f + erff(a * 0.70710678f));
      ou[cc].s[ch] = f2bf(ge * accB[cc]);
    }
  }
#pragma unroll
  for (int cc = 0; cc < 4; ++cc) {
    int pix = (ty0 + r) * 128 + cg + cc;
    *(uint2*)(gxt + (size_t)pix * 352 + c0) = ou[cc].q;
  }
}

// ---------------------------------------------------------------------------
extern "C" void kernel_launch(void* const* d_in, const int* in_sizes, int n_in,
                              void* d_out, int out_size, void* d_ws, size_t ws_size,
                              hipStream_t stream) {
  const float* x        = (const float*)d_in[0];
  const float* ln1_w    = (const float*)d_in[1];
  const float* ln1_b    = (const float*)d_in[2];
  const float* qkvo_w   = (const float*)d_in[3];
  const float* qkvo_b   = (const float*)d_in[4];
  const float* lepe_w   = (const float*)d_in[5];
  const float* lepe_b   = (const float*)d_in[6];
  const float* proj_w   = (const float*)d_in[7];
  const float* proj_b   = (const float*)d_in[8];
  const float* ln2_w    = (const float*)d_in[9];
  const float* ln2_b    = (const float*)d_in[10];
  const float* ffn_in_w = (const float*)d_in[11];
  const float* ffn_dw_w = (const float*)d_in[12];
  const float* ffn_out_w= (const float*)d_in[13];
  float* out = (float*)d_out;

  // workspace layout (bytes)
  const size_t QKVO_OFF = 0;              // 16,777,216 bf16 [512][L]
  const size_t XN_OFF   = 16777216ull;    //  4,194,304 bf16 XT [L][128]
  const size_t LEPE_OFF = 20971520ull;    //  8,388,608 fp32 [128][L]
  const size_t P_OFF    = 29360128ull;    // 22,282,240 bf16 [680][L]
  const size_t G_OFF    = 51642368ull;    // 11,534,336 bf16 XT [L][352]
  const size_t STAT_OFF = 63176704ull;    //     40,960 fp32 [8][16][80]
  const size_t WQ_OFF   = 63217664ull;    //    131,072 bf16 [512][128]
  const size_t WP_OFF   = 63348736ull;    //     32,768 bf16 [128][128]
  const size_t WFI_OFF  = 63381504ull;    //    174,080 bf16 [680][128]
  const size_t WFO_OFF  = 63555584ull;    //     90,112 bf16 [128][352]
  const size_t NEEDED   = 63645696ull;
  if (ws_size < NEEDED) return;

  char* ws = (char*)d_ws;
  short* qbuf  = (short*)(ws + QKVO_OFF);
  short* xnbuf = (short*)(ws + XN_OFF);
  float* lepeb = (float*)(ws + LEPE_OFF);
  short* pbuf  = (short*)(ws + P_OFF);
  short* gxt   = (short*)(ws + G_OFF);
  float* stats = (float*)(ws + STAT_OFF);
  short* wq    = (short*)(ws + WQ_OFF);
  short* wp    = (short*)(ws + WP_OFF);
  short* wfi   = (short*)(ws + WFI_OFF);
  short* wfo   = (short*)(ws + WFO_OFF);

  convert_w<<<dim3((512 * 128 + 255) / 256), 256, 0, stream>>>(qkvo_w, wq, 512, 128, 128);
  convert_w<<<dim3((128 * 128 + 255) / 256), 256, 0, stream>>>(proj_w, wp, 128, 128, 128);
  convert_w<<<dim3((680 * 128 + 255) / 256), 256, 0, stream>>>(ffn_in_w, wfi, 680, 128, 128);
  convert_w<<<dim3((128 * 352 + 255) / 256), 256, 0, stream>>>(ffn_out_w, wfo, 128, 340, 352);
  hipMemsetAsync(stats, 0, 128 * 80 * sizeof(float), stream);

  for (int b = 0; b < BN; ++b) {
    const float* xb   = x   + (size_t)b * C * L;
    float*       outb = out + (size_t)b * C * L;
    float*       st_b = stats + (size_t)b * 16 * 80;

    // K1: LN1 -> xn XT (bf16)
    ln_xt<<<dim3(256), 256, 0, stream>>>(xb, ln1_w, ln1_b, xnbuf);
    // K2: qkvo GEMM (O=512, K=128) -> qbuf bf16 [512][L]
    mfma_gemm<1, 1, 0><<<dim3(128, 8), 256, 0, stream>>>(xnbuf, wq, qbuf,
                                                         qkvo_b, nullptr, 512, 128);
    // K3: lepe dwconv 5x5 on v -> lepe fp32
    dw5_kernel<<<dim3(16, 64), 256, 0, stream>>>(qbuf, lepe_w, lepe_b, lepeb);
    // K4: per-head stats
    kvstats_kernel<<<dim3(16, 16), 256, 0, stream>>>(qbuf, st_b);
    // K5: attention mix -> attn_in XT (bf16, reuse XN)
    attnmix_kernel<<<dim3(64, 16), 256, 0, stream>>>(qbuf, lepeb, st_b, xnbuf);
    // K6: proj GEMM + bias + residual x -> out (fp32 x1)
    mfma_gemm<0, 1, 1><<<dim3(128, 2), 256, 0, stream>>>(xnbuf, wp, outb,
                                                         proj_b, xb, 128, 128);
    // K7: LN2 -> xn2 XT (bf16, reuse XN)
    ln_xt<<<dim3(256), 256, 0, stream>>>(outb, ln2_w, ln2_b, xnbuf);
    // K8: ffn_in GEMM (O=680, K=128) -> p (bf16 [680][L])
    mfma_gemm<1, 0, 0><<<dim3(128, 11), 256, 0, stream>>>(xnbuf, wfi, pbuf,
                                                          nullptr, nullptr, 680, 128);
    // K9: dwconv3x3 + GELU gate -> g XT [L][352] (pad chunks write zeros)
    dw3gate_kernel<<<dim3(16, 88), 256, 0, stream>>>(pbuf, ffn_dw_w, gxt);
    // K10: ffn_out GEMM (O=128, Kp=352) + residual x1 -> out (in place)
    mfma_gemm<0, 0, 1><<<dim3(128, 2), 256, 0, stream>>>(gxt, wfo, outb,
                                                         nullptr, outb, 128, 352);
  }
}

// Round 7
// 806.685 us; speedup vs baseline: 2.2747x; 1.3050x over previous
//
#include <hip/hip_runtime.h>

// ---------------------------------------------------------------------------
// TransformerBlock (linear attention + FFN) on MI355X — bf16 MFMA GEMMs,
// LDS-free GEMM reading pre-transposed activations XT[pixel][c].
// R6: 4-batch groups via blockIdx.z (2 launches per stage), buffer sharing
//     (A = qkvo|ffn_p, B = lepe|gxt), lepe in bf16. ~152.5 MB workspace.
// ---------------------------------------------------------------------------

static constexpr int C   = 128;
static constexpr int L   = 16384;   // 128*128
static constexpr int BN  = 8;       // batch
static constexpr int GB  = 4;       // batches per launch group
static constexpr float SCALE = 0.35355339f;  // 1/sqrt(8)

typedef short bf16x8 __attribute__((ext_vector_type(8)));
typedef float f32x4  __attribute__((ext_vector_type(4)));

union ABFrag { bf16x8 v; uint4 q; };
union U4S8   { uint4 q; short s[8]; };
union U2S4   { uint2 q; short s[4]; };

__device__ inline short f2bf(float f) {
  unsigned u = __float_as_uint(f);
  u += 0x7FFFu + ((u >> 16) & 1u);
  return (short)(u >> 16);
}
__device__ inline float bf2f(short s) {
  return __uint_as_float(((unsigned)(unsigned short)s) << 16);
}

// ------------------------- weight fp32 -> bf16 (K-pad) ---------------------
__global__ __launch_bounds__(256) void convert_w(const float* __restrict__ src,
                                                 short* __restrict__ dst,
                                                 int O, int K, int Kp) {
  int idx = blockIdx.x * 256 + threadIdx.x;
  if (idx >= O * Kp) return;
  int o = idx / Kp, k = idx - o * Kp;
  dst[idx] = (k < K) ? f2bf(src[o * K + k]) : (short)0;
}

// ------------------------------ MFMA GEMM ----------------------------------
// Y[o][l] = sum_k W[o][k] * XT[l][k]  (+bias) (+resid). No LDS.
// Block tile: 128 l x 64 o, 4 waves (2l x 2o), wave = 64l x 32o, BK=32.
// blockIdx.z = batch within group; strides in elements.
template <int OUT_BF16, int HAS_BIAS, int HAS_RESID>
__global__ __launch_bounds__(256) void mfma_gemm(
    const short* __restrict__ XT, const short* __restrict__ Wb,
    void* __restrict__ Yv, const float* __restrict__ bias,
    const float* __restrict__ resid, int O, int Kp,
    size_t xbs, size_t ybs, size_t rbs) {
  const int z = blockIdx.z;
  XT += (size_t)z * xbs;
  if (HAS_RESID) resid += (size_t)z * rbs;
  const int lane = threadIdx.x & 63;
  const int wid  = threadIdx.x >> 6;
  const int wl = wid & 1, wo = wid >> 1;
  const int bl = blockIdx.x * 128;
  const int bo = blockIdx.y * 64;
  const int g   = lane >> 4;
  const int r15 = lane & 15;

  f32x4 acc[4][2];
#pragma unroll
  for (int m = 0; m < 4; ++m)
#pragma unroll
    for (int n = 0; n < 2; ++n) acc[m][n] = (f32x4){0.f, 0.f, 0.f, 0.f};

  const short* xrow[4];
#pragma unroll
  for (int m = 0; m < 4; ++m)
    xrow[m] = XT + (size_t)(bl + wl * 64 + m * 16 + r15) * Kp + g * 8;
  const short* wrow[2];
#pragma unroll
  for (int n = 0; n < 2; ++n)
    wrow[n] = Wb + (size_t)(bo + wo * 32 + n * 16 + r15) * Kp + g * 8;

  for (int k0 = 0; k0 < Kp; k0 += 32) {
    ABFrag a[4], b[2];
#pragma unroll
    for (int m = 0; m < 4; ++m) a[m].q = *(const uint4*)(xrow[m] + k0);
#pragma unroll
    for (int n = 0; n < 2; ++n) b[n].q = *(const uint4*)(wrow[n] + k0);
#pragma unroll
    for (int m = 0; m < 4; ++m)
#pragma unroll
      for (int n = 0; n < 2; ++n)
        acc[m][n] = __builtin_amdgcn_mfma_f32_16x16x32_bf16(a[m].v, b[n].v,
                                                            acc[m][n], 0, 0, 0);
  }

  // epilogue: D col = o (lane&15), D row = pixel ((lane>>4)*4 + reg)
#pragma unroll
  for (int n = 0; n < 2; ++n) {
    int o = bo + wo * 32 + n * 16 + r15;
    if (o >= O) continue;
    float bv = HAS_BIAS ? bias[o] : 0.f;
#pragma unroll
    for (int m = 0; m < 4; ++m) {
      int l = bl + wl * 64 + m * 16 + (g << 2);
      f32x4 v = acc[m][n];
      if (HAS_BIAS) { v[0] += bv; v[1] += bv; v[2] += bv; v[3] += bv; }
      if (HAS_RESID) {
        const float4 r = *(const float4*)(resid + (size_t)o * L + l);
        v[0] += r.x; v[1] += r.y; v[2] += r.z; v[3] += r.w;
      }
      if (OUT_BF16) {
        uint2 s;
        s.x = (unsigned short)f2bf(v[0]) | ((unsigned)(unsigned short)f2bf(v[1]) << 16);
        s.y = (unsigned short)f2bf(v[2]) | ((unsigned)(unsigned short)f2bf(v[3]) << 16);
        *(uint2*)((short*)Yv + (size_t)z * ybs + (size_t)o * L + l) = s;
      } else {
        *(float4*)((float*)Yv + (size_t)z * ybs + (size_t)o * L + l) =
            make_float4(v[0], v[1], v[2], v[3]);
      }
    }
  }
}

// ------------------------------ LayerNorm ----------------------------------
// 4 waves split channels (32 each); 64 pixels per block; bf16 out XT[l][c].
__global__ __launch_bounds__(256) void ln_xt(const float* __restrict__ x,
                                             const float* __restrict__ w,
                                             const float* __restrict__ bias,
                                             short* __restrict__ yt) {
  const int z = blockIdx.z;
  x  += (size_t)z * C * L;
  yt += (size_t)z * L * C;
  const int lane = threadIdx.x & 63;
  const int wv   = threadIdx.x >> 6;      // wave 0..3 -> channels wv*32..+32
  const int l = blockIdx.x * 64 + lane;
  const float* xb = x + l;
  float vals[32];
  float s = 0.f, ss = 0.f;
#pragma unroll
  for (int j = 0; j < 32; ++j) {
    float v = xb[(size_t)(wv * 32 + j) * L];
    vals[j] = v; s += v; ss += v * v;
  }
  __shared__ float red[2][4][64];
  red[0][wv][lane] = s; red[1][wv][lane] = ss;
  __syncthreads();
  float s4 = red[0][0][lane] + red[0][1][lane] + red[0][2][lane] + red[0][3][lane];
  float q4 = red[1][0][lane] + red[1][1][lane] + red[1][2][lane] + red[1][3][lane];
  float mu = s4 * (1.f / C);
  float var = q4 * (1.f / C) - mu * mu;
  float rstd = rsqrtf(var + 1e-5f);
  short* yr = yt + (size_t)l * C + wv * 32;
#pragma unroll
  for (int c0 = 0; c0 < 32; c0 += 8) {
    U4S8 u;
#pragma unroll
    for (int j = 0; j < 8; ++j)
      u.s[j] = f2bf((vals[c0 + j] - mu) * rstd * w[wv * 32 + c0 + j] + bias[wv * 32 + c0 + j]);
    *(uint4*)(yr + c0) = u.q;
  }
}

// ------------------------- lepe: depthwise 5x5 (bf16 in/out) ---------------
// Stripe: 8 rows x 128 cols, 2 channels/block. Coalesced uint4 loads.
__global__ __launch_bounds__(256) void dw5_kernel(const short* __restrict__ qkvo,
                                                  const float* __restrict__ wdw,
                                                  const float* __restrict__ bdw,
                                                  short* __restrict__ outb) {
  const int z = blockIdx.z;
  qkvo += (size_t)z * 512 * L;
  outb += (size_t)z * 128 * L;
  const int ty0 = blockIdx.x * 8;      // 16 row tiles
  const int c0  = blockIdx.y * 2;      // 64 channel pairs
  __shared__ float t[2][12][128];
  __shared__ float wc[2][25];
  const int tid = threadIdx.x;
  if (tid < 50) wc[tid / 25][tid % 25] = wdw[(c0 + tid / 25) * 25 + tid % 25];
  for (int idx = tid; idx < 384; idx += 256) {
    int q = idx & 15, u = idx >> 4;
    int row = u % 12, ch = u / 12;
    int gy = ty0 + row - 2;
    U4S8 v; v.q = make_uint4(0u, 0u, 0u, 0u);
    if (gy >= 0 && gy < 128)
      v.q = *(const uint4*)(qkvo + (size_t)(256 + c0 + ch) * L + gy * 128 + q * 8);
    float4 lo = make_float4(bf2f(v.s[0]), bf2f(v.s[1]), bf2f(v.s[2]), bf2f(v.s[3]));
    float4 hi = make_float4(bf2f(v.s[4]), bf2f(v.s[5]), bf2f(v.s[6]), bf2f(v.s[7]));
    *(float4*)&t[ch][row][q * 8] = lo;
    *(float4*)&t[ch][row][q * 8 + 4] = hi;
  }
  __syncthreads();
  const int r = tid >> 5, cg = (tid & 31) * 4;
#pragma unroll
  for (int ch = 0; ch < 2; ++ch) {
    float acc[4] = {0.f, 0.f, 0.f, 0.f};
#pragma unroll
    for (int i = 0; i < 5; ++i) {
      const float* row = &t[ch][r + i][0];
      float v[8];
      v[0] = (cg - 2 >= 0)   ? row[cg - 2] : 0.f;
      v[1] = (cg - 1 >= 0)   ? row[cg - 1] : 0.f;
      float4 m = *(const float4*)&row[cg];
      v[2] = m.x; v[3] = m.y; v[4] = m.z; v[5] = m.w;
      v[6] = (cg + 4 < 128) ? row[cg + 4] : 0.f;
      v[7] = (cg + 5 < 128) ? row[cg + 5] : 0.f;
#pragma unroll
      for (int cc = 0; cc < 4; ++cc)
#pragma unroll
        for (int j = 0; j < 5; ++j)
          acc[cc] = fmaf(v[cc + j], wc[ch][i * 5 + j], acc[cc]);
    }
    float bv = bdw[c0 + ch];
    U2S4 o;
#pragma unroll
    for (int cc = 0; cc < 4; ++cc) o.s[cc] = f2bf(acc[cc] + bv);
    *(uint2*)(outb + (size_t)(c0 + ch) * L + (ty0 + r) * 128 + cg) = o.q;
  }
}

__device__ inline void theta_shift8(const float* x, const float* sn,
                                    const float* cs, float* o) {
#pragma unroll
  for (int i = 0; i < 4; ++i) {
    float x0 = x[2 * i], x1 = x[2 * i + 1];
    o[2 * i]     = x0 * cs[2 * i]     - x1 * sn[2 * i];
    o[2 * i + 1] = x1 * cs[2 * i + 1] + x0 * sn[2 * i + 1];
  }
}

// rope table: sin/cos of i and i*1e-4 for i in [0,128)
#define ROPE_TABLE_DECL \
  __shared__ float ts0[128], ts4[128], tc0[128], tc4[128];
#define ROPE_TABLE_FILL(tid) \
  if ((tid) < 128) { \
    float s_, c_; \
    sincosf((float)(tid), &s_, &c_); ts0[tid] = s_; tc0[tid] = c_; \
    sincosf((float)(tid) * 1e-4f, &s_, &c_); ts4[tid] = s_; tc4[tid] = c_; \
  }
#define ROPE_LOOKUP(l, sn, cs) { \
    int h_ = (l) >> 7, w_ = (l) & 127; \
    sn[0] = sn[1] = ts0[h_]; sn[2] = sn[3] = ts4[h_]; \
    sn[4] = sn[5] = ts0[w_]; sn[6] = sn[7] = ts4[w_]; \
    cs[0] = cs[1] = tc0[h_]; cs[2] = cs[3] = tc4[h_]; \
    cs[4] = cs[5] = tc0[w_]; cs[6] = cs[7] = tc4[w_]; }

// ------------------- per-head kv / mean_k / mean_v sums --------------------
// grid (16 l-chunks of 1024, 16 heads, GB); 4 px/thread amortizes the reduce.
__global__ __launch_bounds__(256) void kvstats_kernel(const short* __restrict__ qkvo,
                                                      float* __restrict__ stats) {
  const int z = blockIdx.z;
  qkvo  += (size_t)z * 512 * L;
  stats += (size_t)z * 16 * 80;
  int n = blockIdx.y;                 // head 0..15
  int l0 = blockIdx.x * 1024;
  int tid = threadIdx.x;
  ROPE_TABLE_DECL
  ROPE_TABLE_FILL(tid)
  __syncthreads();
  const short* kb = qkvo + (size_t)(128 + n * 8) * L;
  const short* vb = qkvo + (size_t)(256 + n * 8) * L;
  float kv[8][8] = {};
  float mk[8] = {}, mv[8] = {};
  for (int l = l0 + tid; l < l0 + 1024; l += 256) {
    float sn[8], cs[8];
    ROPE_LOOKUP(l, sn, cs)
    float ke[8], kt[8], vv[8];
#pragma unroll
    for (int d = 0; d < 8; ++d) {
      float kval = bf2f(kb[(size_t)d * L + l]);
      ke[d] = kval > 0.f ? kval + 1.f : expf(kval);
      mk[d] += ke[d];
      vv[d] = bf2f(vb[(size_t)d * L + l]);
      mv[d] += vv[d];
    }
    theta_shift8(ke, sn, cs, kt);
#pragma unroll
    for (int d = 0; d < 8; ++d)
#pragma unroll
      for (int e = 0; e < 8; ++e) kv[d][e] = fmaf(kt[d], vv[e], kv[d][e]);
  }
  float valsr[80];
#pragma unroll
  for (int d = 0; d < 8; ++d)
#pragma unroll
    for (int e = 0; e < 8; ++e) valsr[d * 8 + e] = kv[d][e];
#pragma unroll
  for (int d = 0; d < 8; ++d) { valsr[64 + d] = mk[d]; valsr[72 + d] = mv[d]; }
#pragma unroll
  for (int i = 0; i < 80; ++i) {
    float v = valsr[i];
#pragma unroll
    for (int off = 32; off > 0; off >>= 1) v += __shfl_down(v, off);
    valsr[i] = v;
  }
  __shared__ float red[4][80];
  int lane = tid & 63, wid = tid >> 6;
  if (lane == 0) {
#pragma unroll
    for (int i = 0; i < 80; ++i) red[wid][i] = valsr[i];
  }
  __syncthreads();
  if (tid < 80) {
    float s2 = red[0][tid] + red[1][tid] + red[2][tid] + red[3][tid];
    atomicAdd(&stats[n * 80 + tid], s2);
  }
}

// --- attn mix: res = q~·kv*(1+1/z) - z*mean_v; XT out = (res+lepe)*o_gate ---
__global__ __launch_bounds__(256) void attnmix_kernel(const short* __restrict__ qkvo,
                                                      const short* __restrict__ lepe,
                                                      const float* __restrict__ stats,
                                                      short* __restrict__ outt) {
  const int z = blockIdx.z;
  qkvo  += (size_t)z * 512 * L;
  lepe  += (size_t)z * 128 * L;
  stats += (size_t)z * 16 * 80;
  outt  += (size_t)z * L * C;
  int n = blockIdx.y;                 // head 0..15
  int tid = threadIdx.x;
  ROPE_TABLE_DECL
  __shared__ float kvs[64], mks[8], mvs[8];
  ROPE_TABLE_FILL(tid)
  else if (tid < 192)  kvs[tid - 128] = stats[n * 80 + tid - 128] * (SCALE / (float)L);
  else if (tid < 200)  mks[tid - 192] = stats[n * 80 + tid - 128] * (1.f / (float)L);
  else if (tid < 208)  mvs[tid - 200] = stats[n * 80 + tid - 128] * (1.f / (float)L);
  __syncthreads();
  int l = blockIdx.x * 256 + tid;
  const short* qb = qkvo + (size_t)(n * 8) * L + l;
  const short* ob = qkvo + (size_t)(384 + n * 8) * L + l;
  const short* lb = lepe + (size_t)(n * 8) * L + l;
  float qe[8];
#pragma unroll
  for (int d = 0; d < 8; ++d) {
    float qv = bf2f(qb[(size_t)d * L]);
    qe[d] = qv > 0.f ? qv + 1.f : expf(qv);
  }
  float z2 = 0.f;
#pragma unroll
  for (int d = 0; d < 8; ++d) z2 += qe[d] * mks[d];
  z2 *= SCALE;
  float sn[8], cs[8];
  ROPE_LOOKUP(l, sn, cs)
  float qt[8];
  theta_shift8(qe, sn, cs, qt);
  float coef = 1.f + 1.f / (z2 + 1e-6f);
  U4S8 u;
#pragma unroll
  for (int e = 0; e < 8; ++e) {
    float r = 0.f;
#pragma unroll
    for (int d = 0; d < 8; ++d) r = fmaf(qt[d], kvs[d * 8 + e], r);
    float res = r * coef - z2 * mvs[e];
    u.s[e] = f2bf((res + bf2f(lb[(size_t)e * L])) * bf2f(ob[(size_t)e * L]));
  }
  *(uint4*)(outt + (size_t)l * C + n * 8) = u.q;   // XT[l][n*8..n*8+8)
}

// ---------------- FFN: depthwise 3x3 + GELU gate -> XT[l][352] -------------
// Stripe: 8 rows x 128 cols; 4 output channels (both halves) per block.
__global__ __launch_bounds__(256) void dw3gate_kernel(const short* __restrict__ p,
                                                      const float* __restrict__ wdw,
                                                      short* __restrict__ gxt) {
  const int z = blockIdx.z;
  p   += (size_t)z * 680 * L;
  gxt += (size_t)z * L * 352;
  const int ty0 = blockIdx.x * 8;      // 16 row tiles
  const int c0  = blockIdx.y * 4;      // 88 chunks (incl. zero pad 340..351)
  __shared__ short tile[8][10][128];   // slot = half*4+ch, 20KB
  __shared__ float wt[8][9];
  const int tid = threadIdx.x;
  if (tid < 72) {
    int slot = tid / 9, j = tid % 9;
    int half = slot >> 2, cc = c0 + (slot & 3);
    wt[slot][j] = (cc < 340) ? wdw[(half * 340 + cc) * 9 + j] : 0.f;
  }
  for (int idx = tid; idx < 1280; idx += 256) {
    int q = idx & 15, u = idx >> 4;       // u: 0..79
    int row = u % 10, slot = u / 10;      // slot: 0..7
    int cc = c0 + (slot & 3), half = slot >> 2;
    int gy = ty0 + row - 1;
    uint4 v = make_uint4(0u, 0u, 0u, 0u);
    if (cc < 340 && gy >= 0 && gy < 128)
      v = *(const uint4*)(p + (size_t)(half * 340 + cc) * L + gy * 128 + q * 8);
    *(uint4*)&tile[slot][row][q * 8] = v;
  }
  __syncthreads();
  const int r = tid >> 5, cg = (tid & 31) * 4;
  U2S4 ou[4];
#pragma unroll
  for (int ch = 0; ch < 4; ++ch) {
    float accA[4] = {0.f, 0.f, 0.f, 0.f};
    float accB[4] = {0.f, 0.f, 0.f, 0.f};
#pragma unroll
    for (int half = 0; half < 2; ++half) {
      float* acc = half ? accB : accA;
      const float* w9 = wt[half * 4 + ch];
#pragma unroll
      for (int i = 0; i < 3; ++i) {
        const short* row = &tile[half * 4 + ch][r + i][0];
        float v[6];
        v[0] = (cg - 1 >= 0) ? bf2f(row[cg - 1]) : 0.f;
        U2S4 m; m.q = *(const uint2*)&row[cg];
        v[1] = bf2f(m.s[0]); v[2] = bf2f(m.s[1]);
        v[3] = bf2f(m.s[2]); v[4] = bf2f(m.s[3]);
        v[5] = (cg + 4 < 128) ? bf2f(row[cg + 4]) : 0.f;
#pragma unroll
        for (int cc = 0; cc < 4; ++cc)
#pragma unroll
          for (int j = 0; j < 3; ++j)
            acc[cc] = fmaf(v[cc + j], w9[i * 3 + j], acc[cc]);
      }
    }
#pragma unroll
    for (int cc = 0; cc < 4; ++cc) {
      float a = accA[cc];
      float ge = 0.5f * a * (1.f + erff(a * 0.70710678f));
      ou[cc].s[ch] = f2bf(ge * accB[cc]);
    }
  }
#pragma unroll
  for (int cc = 0; cc < 4; ++cc) {
    int pix = (ty0 + r) * 128 + cg + cc;
    *(uint2*)(gxt + (size_t)pix * 352 + c0) = ou[cc].q;
  }
}

// ---------------------------------------------------------------------------
extern "C" void kernel_launch(void* const* d_in, const int* in_sizes, int n_in,
                              void* d_out, int out_size, void* d_ws, size_t ws_size,
                              hipStream_t stream) {
  const float* x        = (const float*)d_in[0];
  const float* ln1_w    = (const float*)d_in[1];
  const float* ln1_b    = (const float*)d_in[2];
  const float* qkvo_w   = (const float*)d_in[3];
  const float* qkvo_b   = (const float*)d_in[4];
  const float* lepe_w   = (const float*)d_in[5];
  const float* lepe_b   = (const float*)d_in[6];
  const float* proj_w   = (const float*)d_in[7];
  const float* proj_b   = (const float*)d_in[8];
  const float* ln2_w    = (const float*)d_in[9];
  const float* ln2_b    = (const float*)d_in[10];
  const float* ffn_in_w = (const float*)d_in[11];
  const float* ffn_dw_w = (const float*)d_in[12];
  const float* ffn_out_w= (const float*)d_in[13];
  float* out = (float*)d_out;

  // element strides per batch
  const size_t QKVO_S = (size_t)512 * L;   // bf16
  const size_t P_S    = (size_t)680 * L;   // bf16
  const size_t XN_S   = (size_t)L * 128;   // bf16
  const size_t LEPE_S = (size_t)128 * L;   // bf16
  const size_t GXT_S  = (size_t)L * 352;   // bf16
  const size_t XCL_S  = (size_t)C * L;     // fp32

  // workspace layout (bytes): A = qkvo|p (per group), B = lepe|gxt
  const size_t A_OFF    = 0;               // 89,128,960 = GB * 680*L*2
  const size_t XN_OFF   = 89128960ull;     // 16,777,216 = GB * L*128*2
  const size_t B_OFF    = 105906176ull;    // 46,137,344 = GB * L*352*2
  const size_t STAT_OFF = 152043520ull;    //     40,960
  const size_t WQ_OFF   = 152084480ull;    //    131,072
  const size_t WP_OFF   = 152215552ull;    //     32,768
  const size_t WFI_OFF  = 152248320ull;    //    174,080
  const size_t WFO_OFF  = 152422400ull;    //     90,112
  const size_t NEEDED   = 152512512ull;    // ~152.5 MB
  if (ws_size < NEEDED) return;

  char* ws = (char*)d_ws;
  short* qbuf  = (short*)(ws + A_OFF);     // [GB][512][L] bf16
  short* pbuf  = (short*)(ws + A_OFF);     // [GB][680][L] bf16 (shared)
  short* xnbuf = (short*)(ws + XN_OFF);    // [GB] XT [L][128]
  short* lepeb = (short*)(ws + B_OFF);     // [GB][128][L] bf16
  short* gxt   = (short*)(ws + B_OFF);     // [GB] XT [L][352] (shared)
  float* stats = (float*)(ws + STAT_OFF);
  short* wq    = (short*)(ws + WQ_OFF);
  short* wp    = (short*)(ws + WP_OFF);
  short* wfi   = (short*)(ws + WFI_OFF);
  short* wfo   = (short*)(ws + WFO_OFF);

  convert_w<<<dim3((512 * 128 + 255) / 256), 256, 0, stream>>>(qkvo_w, wq, 512, 128, 128);
  convert_w<<<dim3((128 * 128 + 255) / 256), 256, 0, stream>>>(proj_w, wp, 128, 128, 128);
  convert_w<<<dim3((680 * 128 + 255) / 256), 256, 0, stream>>>(ffn_in_w, wfi, 680, 128, 128);
  convert_w<<<dim3((128 * 352 + 255) / 256), 256, 0, stream>>>(ffn_out_w, wfo, 128, 340, 352);
  hipMemsetAsync(stats, 0, 128 * 80 * sizeof(float), stream);

  for (int gb = 0; gb < BN / GB; ++gb) {
    const float* xg   = x   + (size_t)gb * GB * XCL_S;
    float*       outg = out + (size_t)gb * GB * XCL_S;
    float*       st_g = stats + (size_t)gb * GB * 16 * 80;

    // K1: LN1 -> xn XT (bf16)
    ln_xt<<<dim3(256, 1, GB), 256, 0, stream>>>(xg, ln1_w, ln1_b, xnbuf);
    // K2: qkvo GEMM (O=512, K=128) -> qbuf bf16 [512][L]
    mfma_gemm<1, 1, 0><<<dim3(128, 8, GB), 256, 0, stream>>>(
        xnbuf, wq, qbuf, qkvo_b, nullptr, 512, 128, XN_S, QKVO_S, 0);
    // K3: lepe dwconv 5x5 on v -> lepe bf16
    dw5_kernel<<<dim3(16, 64, GB), 256, 0, stream>>>(qbuf, lepe_w, lepe_b, lepeb);
    // K4: per-head stats
    kvstats_kernel<<<dim3(16, 16, GB), 256, 0, stream>>>(qbuf, st_g);
    // K5: attention mix -> attn_in XT (bf16, reuse XN)
    attnmix_kernel<<<dim3(64, 16, GB), 256, 0, stream>>>(qbuf, lepeb, st_g, xnbuf);
    // K6: proj GEMM + bias + residual x -> out (fp32 x1)
    mfma_gemm<0, 1, 1><<<dim3(128, 2, GB), 256, 0, stream>>>(
        xnbuf, wp, outg, proj_b, xg, 128, 128, XN_S, XCL_S, XCL_S);
    // K7: LN2 -> xn2 XT (bf16, reuse XN)
    ln_xt<<<dim3(256, 1, GB), 256, 0, stream>>>(outg, ln2_w, ln2_b, xnbuf);
    // K8: ffn_in GEMM (O=680, K=128) -> p (bf16 [680][L], reuse A)
    mfma_gemm<1, 0, 0><<<dim3(128, 11, GB), 256, 0, stream>>>(
        xnbuf, wfi, pbuf, nullptr, nullptr, 680, 128, XN_S, P_S, 0);
    // K9: dwconv3x3 + GELU gate -> g XT [L][352] (pad chunks write zeros)
    dw3gate_kernel<<<dim3(16, 88, GB), 256, 0, stream>>>(pbuf, ffn_dw_w, gxt);
    // K10: ffn_out GEMM (O=128, Kp=352) + residual x1 -> out (in place)
    mfma_gemm<0, 0, 1><<<dim3(128, 2, GB), 256, 0, stream>>>(
        gxt, wfo, outg, nullptr, outg, 128, 352, GXT_S, XCL_S, XCL_S);
  }
}